// Round 6
// baseline (128.150 us; speedup 1.0000x reference)
//
#include <hip/hip_runtime.h>
#include <math.h>

#define NN 4096
#define HH 8
constexpr float SCALE = 0.17677669529663687f;   // 1/sqrt(32)
constexpr float LOG2E = 1.4426950408889634f;
constexpr float SC2   = SCALE * LOG2E;          // folded into Q columns of Wqkv

typedef __bf16 bf16;
typedef __bf16 bf16x8 __attribute__((ext_vector_type(8)));
typedef __bf16 bf16x4 __attribute__((ext_vector_type(4)));
typedef __bf16 bf16x2 __attribute__((ext_vector_type(2)));
typedef float  f32x4  __attribute__((ext_vector_type(4)));
typedef unsigned u32;
typedef unsigned u32x4 __attribute__((ext_vector_type(4)));

#define MFMA(a, b, c) __builtin_amdgcn_mfma_f32_16x16x32_bf16((a), (b), (c), 0, 0, 0)

// pack two f32 -> one u32 of 2 bf16 (compiler emits v_cvt_pk_bf16_f32)
__device__ __forceinline__ u32 pkbf(float lo, float hi) {
    bf16x2 t;
    t[0] = (bf16)lo;
    t[1] = (bf16)hi;
    return __builtin_bit_cast(u32, t);
}

// ---------------------------------------------------------------------------
// W [K][N] fp32 -> W^T hi/lo bf16 [N][K] (used for the Wout piggyback only).
// ---------------------------------------------------------------------------
template <int K, int N, bool SCALEQ>
__device__ __forceinline__ void wcast_body(const float* __restrict__ W,
                                           bf16* __restrict__ WhT,
                                           bf16* __restrict__ WlT,
                                           int n0, int k0, int t,
                                           float (*tile)[65]) {
#pragma unroll
    for (int p = 0; p < 16; ++p) {
        const int r = p * 4 + (t >> 6);
        const int c = t & 63;
        tile[r][c] = W[(size_t)(k0 + r) * N + n0 + c];
    }
    __syncthreads();
    const int nr = t >> 2, kc0 = (t & 3) * 16;
    const float sc = (SCALEQ && (n0 + nr) < 256) ? SC2 : 1.0f;
    bf16x8 h[2], l[2];
#pragma unroll
    for (int g = 0; g < 2; ++g)
#pragma unroll
        for (int j = 0; j < 8; ++j) {
            const float v = tile[kc0 + g * 8 + j][nr] * sc;
            const bf16 hh = (bf16)v;
            h[g][j] = hh;
            l[g][j] = (bf16)(v - (float)hh);
        }
    const size_t ob = (size_t)(n0 + nr) * K + k0 + kc0;
    *(bf16x8*)&WhT[ob] = h[0];
    *(bf16x8*)&WhT[ob + 8] = h[1];
    *(bf16x8*)&WlT[ob] = l[0];
    *(bf16x8*)&WlT[ob + 8] = l[1];
}

// ---------------------------------------------------------------------------
// Fused QKV GEMM, "ct-triple" edition (round-4, proven).
// Grid (32, 8): block (mb, g) computes ct = {g, 8+g, 16+g}; A cast once.
// ---------------------------------------------------------------------------
__global__ __launch_bounds__(256, 2) void gemmqkv_kernel(
    const float* __restrict__ A, const float* __restrict__ Wqkv,
    const float* __restrict__ bqkv,
    const float* __restrict__ pe, const float* __restrict__ Wpe,
    const float* __restrict__ bpe, const float* __restrict__ Wout,
    bf16* __restrict__ Qb, bf16* __restrict__ Kf, bf16* __restrict__ Vf,
    bf16* __restrict__ WouthT, bf16* __restrict__ WoutlT) {
    const int t = threadIdx.x, wave = t >> 6, lane = t & 63;
    const int quad = lane >> 4, i16 = lane & 15;
    const int mb = blockIdx.x, g = blockIdx.y;

    __shared__ __align__(16) bf16 Bs[2][32 * 512];  // 2 x 32 KB B panel (dbuf)
    __shared__ __align__(16) bf16 Ctl[128 * 36];    // 9 KB C tile, stride 36
    __shared__ float eps[128];

    const int m0 = mb * 128 + wave * 32;

    // --- B panel staging with inline hi/lo cast (identical math to round 3)
    auto stage_panel = [&](bf16* bs, int ct) {
        const int i16l = lane & 15, ql = lane >> 4;
        const float sc = (ct < 8) ? SC2 : 1.0f;
        const int n0 = ct * 32;
#pragma unroll
        for (int cc = wave; cc < 16; cc += 4) {
            const int nsi = cc >> 3, kc = cc & 7;
            const int n = n0 + nsi * 16 + i16l;
            const int kk = kc * 32 + ql * 8;
            bf16x8 h, l;
#pragma unroll
            for (int j = 0; j < 8; ++j) {
                const float v = Wqkv[(size_t)(kk + j) * 768 + n] * sc;
                const bf16 hh = (bf16)v;
                h[j] = hh;
                l[j] = (bf16)(v - (float)hh);
            }
            *(bf16x8*)&bs[cc * 512 + lane * 8] = h;
            *(bf16x8*)&bs[(cc + 16) * 512 + lane * 8] = l;
        }
    };

    // --- A fragments with inline hi/lo split — ONCE per block
    bf16x8 ah[2][8], al[2][8];
#pragma unroll
    for (int ms = 0; ms < 2; ++ms) {
        const int row = m0 + ms * 16 + i16;
#pragma unroll
        for (int kc = 0; kc < 8; ++kc) {
            const size_t ab = (size_t)row * 256 + kc * 32 + quad * 8;
            const f32x4 u0 = *(const f32x4*)&A[ab];
            const f32x4 u1 = *(const f32x4*)&A[ab + 4];
#pragma unroll
            for (int e = 0; e < 4; ++e) {
                const bf16 h0 = (bf16)u0[e], h1 = (bf16)u1[e];
                ah[ms][kc][e] = h0;
                ah[ms][kc][e + 4] = h1;
                al[ms][kc][e] = (bf16)(u0[e] - (float)h0);
                al[ms][kc][e + 4] = (bf16)(u1[e] - (float)h1);
            }
        }
    }

    auto run_tile = [&](const bf16* bs, f32x4 (&acc)[2][2]) {
#pragma unroll
        for (int nsi = 0; nsi < 2; ++nsi) {
            acc[nsi][0] = f32x4{0.f, 0.f, 0.f, 0.f};
            acc[nsi][1] = f32x4{0.f, 0.f, 0.f, 0.f};
#pragma unroll
            for (int kc = 0; kc < 8; ++kc) {
                const bf16x8 bh = *(const bf16x8*)&bs[(nsi * 8 + kc) * 512 + lane * 8];
                const bf16x8 bl = *(const bf16x8*)&bs[((2 + nsi) * 8 + kc) * 512 + lane * 8];
                acc[nsi][0] = MFMA(ah[0][kc], bh, acc[nsi][0]);
                acc[nsi][0] = MFMA(ah[0][kc], bl, acc[nsi][0]);
                acc[nsi][0] = MFMA(al[0][kc], bh, acc[nsi][0]);
                acc[nsi][1] = MFMA(ah[1][kc], bh, acc[nsi][1]);
                acc[nsi][1] = MFMA(ah[1][kc], bl, acc[nsi][1]);
                acc[nsi][1] = MFMA(al[1][kc], bh, acc[nsi][1]);
            }
        }
    };

    stage_panel(Bs[0], g);                 // Q panel
    if (t < 128) {   // pe-projection for head g / this token tile (V phase)
        const int n = mb * 128 + t;
        float acc = bpe[g];
#pragma unroll
        for (int k = 0; k < 16; ++k) acc += pe[n * 16 + k] * Wpe[k * 8 + g];
        eps[t] = __builtin_amdgcn_exp2f(-acc * LOG2E - 8.0f);
    }
    __syncthreads();                       // Bs[0] ready

    // ---- Phase Q (ct = g) ----
    stage_panel(Bs[1], 8 + g);             // prefetch K panel
    {
        f32x4 acc[2][2];
        run_tile(Bs[0], acc);
        const int n0 = g * 32;
#pragma unroll
        for (int nsi = 0; nsi < 2; ++nsi) {
            const int n = n0 + nsi * 16 + i16;
            const float b = bqkv[n] * SC2;
#pragma unroll
            for (int ms = 0; ms < 2; ++ms)
#pragma unroll
                for (int r = 0; r < 4; ++r)
                    Qb[(size_t)(m0 + ms * 16 + quad * 4 + r) * 256 + n] =
                        (bf16)(acc[nsi][ms][r] + b);
        }
    }
    __syncthreads();                       // Bs[1] ready; Bs[0] reads done

    // ---- Phase K (ct = 8+g, head g) ----
    stage_panel(Bs[0], 16 + g);            // prefetch V panel (Bs[0] free)
    {
        f32x4 acc[2][2];
        run_tile(Bs[1], acc);
        const int n0 = (8 + g) * 32;
#pragma unroll
        for (int nsi = 0; nsi < 2; ++nsi) {
            const int n = n0 + nsi * 16 + i16;
            const float b = bqkv[n];
#pragma unroll
            for (int ms = 0; ms < 2; ++ms)
#pragma unroll
                for (int r = 0; r < 4; ++r)
                    Ctl[(wave * 32 + ms * 16 + quad * 4 + r) * 36 + nsi * 16 + i16] =
                        (bf16)(acc[nsi][ms][r] + b);
        }
        __syncthreads();                   // Ctl ready (also: Bs[0] staged)
        // K frags: 8 chunks (2 key tiles x 4 key-subs), transpose reads
#pragma unroll
        for (int c = wave; c < 8; c += 4) {
            const int half = c >> 2, s = c & 3;
            bf16x8 o;
#pragma unroll
            for (int j = 0; j < 8; ++j)
                o[j] = Ctl[(half * 64 + s * 16 + i16) * 36 + quad * 8 + j];
            *(bf16x8*)&Kf[((size_t)(g * 64 + mb * 2 + half) * 4 + s) * 512 + lane * 8] = o;
        }
    }
    __syncthreads();                       // K-transpose reads of Ctl done

    // ---- Phase V (ct = 16+g, head g) ----
    {
        f32x4 acc[2][2];
        run_tile(Bs[0], acc);
        const int n0 = (16 + g) * 32;
#pragma unroll
        for (int nsi = 0; nsi < 2; ++nsi) {
            const int n = n0 + nsi * 16 + i16;
            const float b = bqkv[n];
#pragma unroll
            for (int ms = 0; ms < 2; ++ms)
#pragma unroll
                for (int r = 0; r < 4; ++r)
                    Ctl[(wave * 32 + ms * 16 + quad * 4 + r) * 36 + nsi * 16 + i16] =
                        (bf16)(acc[nsi][ms][r] + b);
        }
        __syncthreads();                   // Ctl ready; Bs[0] reads done
        // V'' frags: 12 chunks, ep-scaled, ep-row at dim'=32 (softmax-l trick)
#pragma unroll
        for (int c = wave; c < 12; c += 4) {
            const int half = c / 6, ch = c % 6;
            const int dt = ch >> 1, kc = ch & 1;
            const int dimp = dt * 16 + i16;
            bf16x8 o;
#pragma unroll
            for (int j = 0; j < 8; ++j) {
                const int key = half * 64 + kc * 32 + quad * 8 + j; // local
                float v;
                if (dimp < 32)       v = (float)Ctl[key * 36 + dimp] * eps[key];
                else if (dimp == 32) v = eps[key];
                else                 v = 0.f;
                o[j] = (bf16)v;
            }
            *(bf16x8*)&Vf[((size_t)(g * 64 + mb * 2 + half) * 6 + ch) * 512 + lane * 8] = o;
        }
    }

    // ---- Wout cast piggyback (16 tiles ride the g==7 blocks' tail) ----
    if (g == 7 && mb < 16) {
        __syncthreads();
        wcast_body<256, 256, false>(Wout, WouthT, WoutlT,
                                    (mb % 4) * 64, (mb / 4) * 64, t,
                                    (float(*)[65]) & Bs[0][0]);
    }
}

// ---------------------------------------------------------------------------
// Staged 3-term split-bf16 GEMM — out proj.  ROUND-4 EXACT VERSION (proven at
// 121.46): NTILE=16, grid (32,16) = 512 blocks (2/CU, 2 waves/SIMD), two
// independent accumulator chains per wave.  Round-5's (64,4)/NTILE=64 retile
// regressed: 1 block/CU + single-chain serial MFMA latency fully exposed.
// ---------------------------------------------------------------------------
template <int NOUT, int NTILE, typename OT>
__global__ __launch_bounds__(256, 2) void gemm3s_kernel(const bf16* __restrict__ Ah,
                                                        const bf16* __restrict__ Al,
                                                        const bf16* __restrict__ BhT,
                                                        const bf16* __restrict__ BlT,
                                                        const float* __restrict__ bias,
                                                        OT* __restrict__ C) {
    constexpr int NS = NTILE / 16;
    const int t = threadIdx.x, wave = t >> 6, lane = t & 63;
    const int quad = lane >> 4, i16 = lane & 15;
    const int m0 = blockIdx.x * 128 + wave * 32;
    const int n0 = blockIdx.y * NTILE;

    __shared__ __align__(16) bf16 Bs[NTILE * 512];

    {
        const int l = t & 63, i16l = l & 15, ql = l >> 4;
#pragma unroll
        for (int c = t >> 6; c < NS * 16; c += 4) {
            const bool lo = c >= NS * 8;
            const int cc = lo ? c - NS * 8 : c;
            const int nsi = cc >> 3, kc = cc & 7;
            const bf16* src = (lo ? BlT : BhT) +
                (size_t)(n0 + nsi * 16 + i16l) * 256 + kc * 32 + ql * 8;
            *(uint4*)&Bs[c * 512 + l * 8] = *(const uint4*)src;
        }
    }

    bf16x8 ah[2][8], al[2][8];
#pragma unroll
    for (int ms = 0; ms < 2; ++ms) {
        const size_t abase = (size_t)(m0 + ms * 16 + i16) * 256 + quad * 8;
#pragma unroll
        for (int kc = 0; kc < 8; ++kc) {
            ah[ms][kc] = *(const bf16x8*)&Ah[abase + kc * 32];
            al[ms][kc] = *(const bf16x8*)&Al[abase + kc * 32];
        }
    }
    __syncthreads();

#pragma unroll
    for (int nsi = 0; nsi < NS; ++nsi) {
        f32x4 acc[2];
        acc[0] = f32x4{0.f, 0.f, 0.f, 0.f};
        acc[1] = f32x4{0.f, 0.f, 0.f, 0.f};
#pragma unroll
        for (int kc = 0; kc < 8; ++kc) {
            const bf16x8 bh = *(const bf16x8*)&Bs[(nsi * 8 + kc) * 512 + lane * 8];
            const bf16x8 bl = *(const bf16x8*)&Bs[((NS + nsi) * 8 + kc) * 512 + lane * 8];
            acc[0] = MFMA(ah[0][kc], bh, acc[0]);
            acc[0] = MFMA(ah[0][kc], bl, acc[0]);
            acc[0] = MFMA(al[0][kc], bh, acc[0]);
            acc[1] = MFMA(ah[1][kc], bh, acc[1]);
            acc[1] = MFMA(ah[1][kc], bl, acc[1]);
            acc[1] = MFMA(al[1][kc], bh, acc[1]);
        }
        const int n = n0 + nsi * 16 + i16;
        const float b = bias[n];
#pragma unroll
        for (int ms = 0; ms < 2; ++ms)
#pragma unroll
            for (int r = 0; r < 4; ++r)
                C[(size_t)(m0 + ms * 16 + quad * 4 + r) * NOUT + n] = (OT)(acc[ms][r] + b);
    }
}

// ---------------------------------------------------------------------------
// Fixed-m flash attention, permlane edition, (512,2)+volatile (passed R5's
// numeric check; this round isolates its PERF effect vs round-4's (512,4):
// the round-1 body needs ~160-180 live VGPRs, the 128-cap forced scratch
// spills; (512,2) trades 4->2 waves/SIMD for a spill-free loop).
// ---------------------------------------------------------------------------
__global__ __launch_bounds__(512, 2) void attn_kernel(const bf16* __restrict__ Qb,
                                                      const bf16* __restrict__ Kf,
                                                      const bf16* __restrict__ Vf,
                                                      bf16* __restrict__ aoh,
                                                      bf16* __restrict__ aol) {
    const int t = threadIdx.x, w = t >> 6, lane = t & 63;
    const int quad = lane >> 4, i16 = lane & 15;
    const int qb = blockIdx.y, h = blockIdx.x;

    __shared__ __align__(16) float M[8][2112];   // 67.6 KB epilogue merge

    const int q0 = qb * 64;
    bf16x8 qf[4];
#pragma unroll
    for (int qs = 0; qs < 4; ++qs)
        qf[qs] = *(const bf16x8*)&Qb[(size_t)(q0 + qs * 16 + i16) * 256 + h * 32 + quad * 8];

    f32x4 o[3][4];
#pragma unroll
    for (int dt = 0; dt < 3; ++dt)
#pragma unroll
        for (int qs = 0; qs < 4; ++qs) o[dt][qs] = f32x4{0.f, 0.f, 0.f, 0.f};

    const bf16* kb = Kf + (size_t)(h * 64) * 2048 + lane * 8;
    const bf16* vb = Vf + (size_t)(h * 64) * 3072 + lane * 8;

    const int kt0 = w * 8;
    for (int it = 0; it < 8; ++it) {
        const int kt = kt0 + it;
        bf16x8 kcur[4];
#pragma unroll
        for (int s = 0; s < 4; ++s)
            kcur[s] = *(const bf16x8*)&kb[((size_t)kt * 4 + s) * 512];

        const f32x4 z = {0.f, 0.f, 0.f, 0.f};
        u32x4 P[4][2];   // [qs][32-key half] -> PV B-frag words (all static idx)
#pragma unroll
        for (int qh = 0; qh < 2; ++qh) {
            f32x4 sf[2][4];
#pragma unroll
            for (int ks = 0; ks < 4; ++ks) {
                sf[0][ks] = MFMA(kcur[ks], qf[qh * 2 + 0], z);
                sf[1][ks] = MFMA(kcur[ks], qf[qh * 2 + 1], z);
            }
#pragma unroll
            for (int qi = 0; qi < 2; ++qi) {
                const int qs = qh * 2 + qi;
#pragma unroll
                for (int h2 = 0; h2 < 2; ++h2) {
                    const f32x4 s0 = sf[qi][2 * h2 + 0];
                    const f32x4 s1 = sf[qi][2 * h2 + 1];
                    u32 a = pkbf(__builtin_amdgcn_exp2f(s0[0]),
                                 __builtin_amdgcn_exp2f(s0[1]));
                    u32 b = pkbf(__builtin_amdgcn_exp2f(s0[2]),
                                 __builtin_amdgcn_exp2f(s0[3]));
                    u32 c = pkbf(__builtin_amdgcn_exp2f(s1[0]),
                                 __builtin_amdgcn_exp2f(s1[1]));
                    u32 d = pkbf(__builtin_amdgcn_exp2f(s1[2]),
                                 __builtin_amdgcn_exp2f(s1[3]));
                    asm volatile("v_permlane32_swap_b32 %0, %1" : "+v"(a), "+v"(c));
                    asm volatile("v_permlane16_swap_b32 %0, %1" : "+v"(a), "+v"(c));
                    asm volatile("v_permlane32_swap_b32 %0, %1" : "+v"(b), "+v"(d));
                    asm volatile("v_permlane16_swap_b32 %0, %1" : "+v"(b), "+v"(d));
                    P[qs][h2] = u32x4{a, b, c, d};
                }
            }
        }

        bf16x8 vv[6];
#pragma unroll
        for (int c = 0; c < 6; ++c)
            vv[c] = *(const bf16x8*)&vb[((size_t)kt * 6 + c) * 512];

#pragma unroll
        for (int qs = 0; qs < 4; ++qs) {
            const bf16x8 pb0 = __builtin_bit_cast(bf16x8, P[qs][0]);
            const bf16x8 pb1 = __builtin_bit_cast(bf16x8, P[qs][1]);
#pragma unroll
            for (int dt = 0; dt < 3; ++dt) {
                o[dt][qs] = MFMA(vv[dt * 2 + 0], pb0, o[dt][qs]);
                o[dt][qs] = MFMA(vv[dt * 2 + 1], pb1, o[dt][qs]);
            }
        }
    }

    {
        float* myo = &M[w][0];
#pragma unroll
        for (int qs = 0; qs < 4; ++qs) {
            *(f32x4*)&myo[(qs * 64 + lane) * 8 + 0] = o[0][qs];
            *(f32x4*)&myo[(qs * 64 + lane) * 8 + 4] = o[1][qs];
        }
        if (quad == 0) {
#pragma unroll
            for (int qs = 0; qs < 4; ++qs)
                myo[2048 + qs * 16 + i16] = o[2][qs][0];
        }
    }
    __syncthreads();
    if (w < 4) {
        f32x4 a0 = {0.f, 0.f, 0.f, 0.f}, a1 = {0.f, 0.f, 0.f, 0.f};
        float lsum = 0.f;
#pragma unroll
        for (int ww = 0; ww < 8; ++ww) {
            const float* p = &M[ww][0];
            a0 += *(const f32x4*)&p[(w * 64 + lane) * 8 + 0];
            a1 += *(const f32x4*)&p[(w * 64 + lane) * 8 + 4];
            if (lane < 16) lsum += p[2048 + w * 16 + lane];
        }
        const float linv = 1.0f / __shfl(lsum, i16, 64);
        const int row = q0 + w * 16 + i16;
#pragma unroll
        for (int dt = 0; dt < 2; ++dt) {
            const f32x4 src = dt ? a1 : a0;
            bf16x4 hi, lo;
#pragma unroll
            for (int r = 0; r < 4; ++r) {
                const float v = src[r] * linv;
                hi[r] = (bf16)v;
                lo[r] = (bf16)(v - (float)hi[r]);
            }
            const size_t ob = (size_t)row * 256 + h * 32 + dt * 16 + quad * 4;
            *(bf16x4*)&aoh[ob] = hi;
            *(bf16x4*)&aol[ob] = lo;
        }
    }
}

// ---------------------------------------------------------------------------
extern "C" void kernel_launch(void* const* d_in, const int* in_sizes, int n_in,
                              void* d_out, int out_size, void* d_ws, size_t ws_size,
                              hipStream_t stream) {
    const float* x    = (const float*)d_in[0];
    const float* pe   = (const float*)d_in[1];
    const float* Wqkv = (const float*)d_in[2];
    const float* bqkv = (const float*)d_in[3];
    const float* Wpe  = (const float*)d_in[4];
    const float* bpe  = (const float*)d_in[5];
    const float* Wout = (const float*)d_in[6];
    const float* bout = (const float*)d_in[7];
    float* out = (float*)d_out;

    char* ws = (char*)d_ws;
    // first 768 KB intentionally unused (was WqkvhT/lT; cast is now inline)
    bf16*  WouthT  = (bf16*)(ws + 786432);          // 128 KB
    bf16*  WoutlT  = (bf16*)(ws + 917504);          // 128 KB
    bf16*  Qb      = (bf16*)(ws + 1048576);         // 2 MB
    bf16*  Kf      = (bf16*)(ws + 3145728);         // 2 MB
    bf16*  Vf      = (bf16*)(ws + 5242880);         // 3 MB
    bf16*  aoh     = (bf16*)(ws + 8388608);         // 2 MB
    bf16*  aol     = (bf16*)(ws + 10485760);        // 2 MB -> 12.6 MB total

    gemmqkv_kernel<<<dim3(32, 8), 256, 0, stream>>>(x, Wqkv, bqkv,
                                                    pe, Wpe, bpe, Wout,
                                                    Qb, Kf, Vf, WouthT, WoutlT);
    attn_kernel<<<dim3(HH, NN / 64), 512, 0, stream>>>(Qb, Kf, Vf, aoh, aol);
    gemm3s_kernel<256, 16, float><<<dim3(32, 16), 256, 0, stream>>>(aoh, aol, WouthT, WoutlT, bout, out);
}

// Round 7
// 120.385 us; speedup vs baseline: 1.0645x; 1.0645x over previous
//
#include <hip/hip_runtime.h>
#include <math.h>

#define NN 4096
#define HH 8
constexpr float SCALE = 0.17677669529663687f;   // 1/sqrt(32)
constexpr float LOG2E = 1.4426950408889634f;
constexpr float SC2   = SCALE * LOG2E;          // folded into Q columns of Wqkv

typedef __bf16 bf16;
typedef __bf16 bf16x8 __attribute__((ext_vector_type(8)));
typedef __bf16 bf16x4 __attribute__((ext_vector_type(4)));
typedef __bf16 bf16x2 __attribute__((ext_vector_type(2)));
typedef float  f32x4  __attribute__((ext_vector_type(4)));
typedef unsigned u32;
typedef unsigned u32x4 __attribute__((ext_vector_type(4)));

#define MFMA(a, b, c) __builtin_amdgcn_mfma_f32_16x16x32_bf16((a), (b), (c), 0, 0, 0)

// pack two f32 -> one u32 of 2 bf16 (compiler emits v_cvt_pk_bf16_f32)
__device__ __forceinline__ u32 pkbf(float lo, float hi) {
    bf16x2 t;
    t[0] = (bf16)lo;
    t[1] = (bf16)hi;
    return __builtin_bit_cast(u32, t);
}

// ---------------------------------------------------------------------------
// Fused QKV GEMM, "ct-triple" edition (round-4, proven), MINUS the Wout
// piggyback: the 16 tail blocks (g==7, mb<16) used to run a 4th serialized
// wcast phase, finishing last and stretching the gemmqkv->attn edge.  The
// Wout cast now lives inline in gemm3s (same trick as the Wqkv inline cast).
// Grid (32, 8): block (mb, g) computes ct = {g, 8+g, 16+g}; A cast once.
// ---------------------------------------------------------------------------
__global__ __launch_bounds__(256, 2) void gemmqkv_kernel(
    const float* __restrict__ A, const float* __restrict__ Wqkv,
    const float* __restrict__ bqkv,
    const float* __restrict__ pe, const float* __restrict__ Wpe,
    const float* __restrict__ bpe,
    bf16* __restrict__ Qb, bf16* __restrict__ Kf, bf16* __restrict__ Vf) {
    const int t = threadIdx.x, wave = t >> 6, lane = t & 63;
    const int quad = lane >> 4, i16 = lane & 15;
    const int mb = blockIdx.x, g = blockIdx.y;

    __shared__ __align__(16) bf16 Bs[2][32 * 512];  // 2 x 32 KB B panel (dbuf)
    __shared__ __align__(16) bf16 Ctl[128 * 36];    // 9 KB C tile, stride 36
    __shared__ float eps[128];

    const int m0 = mb * 128 + wave * 32;

    // --- B panel staging with inline hi/lo cast (identical math to round 3)
    auto stage_panel = [&](bf16* bs, int ct) {
        const int i16l = lane & 15, ql = lane >> 4;
        const float sc = (ct < 8) ? SC2 : 1.0f;
        const int n0 = ct * 32;
#pragma unroll
        for (int cc = wave; cc < 16; cc += 4) {
            const int nsi = cc >> 3, kc = cc & 7;
            const int n = n0 + nsi * 16 + i16l;
            const int kk = kc * 32 + ql * 8;
            bf16x8 h, l;
#pragma unroll
            for (int j = 0; j < 8; ++j) {
                const float v = Wqkv[(size_t)(kk + j) * 768 + n] * sc;
                const bf16 hh = (bf16)v;
                h[j] = hh;
                l[j] = (bf16)(v - (float)hh);
            }
            *(bf16x8*)&bs[cc * 512 + lane * 8] = h;
            *(bf16x8*)&bs[(cc + 16) * 512 + lane * 8] = l;
        }
    };

    // --- A fragments with inline hi/lo split — ONCE per block
    bf16x8 ah[2][8], al[2][8];
#pragma unroll
    for (int ms = 0; ms < 2; ++ms) {
        const int row = m0 + ms * 16 + i16;
#pragma unroll
        for (int kc = 0; kc < 8; ++kc) {
            const size_t ab = (size_t)row * 256 + kc * 32 + quad * 8;
            const f32x4 u0 = *(const f32x4*)&A[ab];
            const f32x4 u1 = *(const f32x4*)&A[ab + 4];
#pragma unroll
            for (int e = 0; e < 4; ++e) {
                const bf16 h0 = (bf16)u0[e], h1 = (bf16)u1[e];
                ah[ms][kc][e] = h0;
                ah[ms][kc][e + 4] = h1;
                al[ms][kc][e] = (bf16)(u0[e] - (float)h0);
                al[ms][kc][e + 4] = (bf16)(u1[e] - (float)h1);
            }
        }
    }

    auto run_tile = [&](const bf16* bs, f32x4 (&acc)[2][2]) {
#pragma unroll
        for (int nsi = 0; nsi < 2; ++nsi) {
            acc[nsi][0] = f32x4{0.f, 0.f, 0.f, 0.f};
            acc[nsi][1] = f32x4{0.f, 0.f, 0.f, 0.f};
#pragma unroll
            for (int kc = 0; kc < 8; ++kc) {
                const bf16x8 bh = *(const bf16x8*)&bs[(nsi * 8 + kc) * 512 + lane * 8];
                const bf16x8 bl = *(const bf16x8*)&bs[((2 + nsi) * 8 + kc) * 512 + lane * 8];
                acc[nsi][0] = MFMA(ah[0][kc], bh, acc[nsi][0]);
                acc[nsi][0] = MFMA(ah[0][kc], bl, acc[nsi][0]);
                acc[nsi][0] = MFMA(al[0][kc], bh, acc[nsi][0]);
                acc[nsi][1] = MFMA(ah[1][kc], bh, acc[nsi][1]);
                acc[nsi][1] = MFMA(ah[1][kc], bl, acc[nsi][1]);
                acc[nsi][1] = MFMA(al[1][kc], bh, acc[nsi][1]);
            }
        }
    };

    stage_panel(Bs[0], g);                 // Q panel
    if (t < 128) {   // pe-projection for head g / this token tile (V phase)
        const int n = mb * 128 + t;
        float acc = bpe[g];
#pragma unroll
        for (int k = 0; k < 16; ++k) acc += pe[n * 16 + k] * Wpe[k * 8 + g];
        eps[t] = __builtin_amdgcn_exp2f(-acc * LOG2E - 8.0f);
    }
    __syncthreads();                       // Bs[0] ready

    // ---- Phase Q (ct = g) ----
    stage_panel(Bs[1], 8 + g);             // prefetch K panel
    {
        f32x4 acc[2][2];
        run_tile(Bs[0], acc);
        const int n0 = g * 32;
#pragma unroll
        for (int nsi = 0; nsi < 2; ++nsi) {
            const int n = n0 + nsi * 16 + i16;
            const float b = bqkv[n] * SC2;
#pragma unroll
            for (int ms = 0; ms < 2; ++ms)
#pragma unroll
                for (int r = 0; r < 4; ++r)
                    Qb[(size_t)(m0 + ms * 16 + quad * 4 + r) * 256 + n] =
                        (bf16)(acc[nsi][ms][r] + b);
        }
    }
    __syncthreads();                       // Bs[1] ready; Bs[0] reads done

    // ---- Phase K (ct = 8+g, head g) ----
    stage_panel(Bs[0], 16 + g);            // prefetch V panel (Bs[0] free)
    {
        f32x4 acc[2][2];
        run_tile(Bs[1], acc);
        const int n0 = (8 + g) * 32;
#pragma unroll
        for (int nsi = 0; nsi < 2; ++nsi) {
            const int n = n0 + nsi * 16 + i16;
            const float b = bqkv[n];
#pragma unroll
            for (int ms = 0; ms < 2; ++ms)
#pragma unroll
                for (int r = 0; r < 4; ++r)
                    Ctl[(wave * 32 + ms * 16 + quad * 4 + r) * 36 + nsi * 16 + i16] =
                        (bf16)(acc[nsi][ms][r] + b);
        }
        __syncthreads();                   // Ctl ready (also: Bs[0] staged)
        // K frags: 8 chunks (2 key tiles x 4 key-subs), transpose reads
#pragma unroll
        for (int c = wave; c < 8; c += 4) {
            const int half = c >> 2, s = c & 3;
            bf16x8 o;
#pragma unroll
            for (int j = 0; j < 8; ++j)
                o[j] = Ctl[(half * 64 + s * 16 + i16) * 36 + quad * 8 + j];
            *(bf16x8*)&Kf[((size_t)(g * 64 + mb * 2 + half) * 4 + s) * 512 + lane * 8] = o;
        }
    }
    __syncthreads();                       // K-transpose reads of Ctl done

    // ---- Phase V (ct = 16+g, head g) ----
    {
        f32x4 acc[2][2];
        run_tile(Bs[0], acc);
        const int n0 = (16 + g) * 32;
#pragma unroll
        for (int nsi = 0; nsi < 2; ++nsi) {
            const int n = n0 + nsi * 16 + i16;
            const float b = bqkv[n];
#pragma unroll
            for (int ms = 0; ms < 2; ++ms)
#pragma unroll
                for (int r = 0; r < 4; ++r)
                    Ctl[(wave * 32 + ms * 16 + quad * 4 + r) * 36 + nsi * 16 + i16] =
                        (bf16)(acc[nsi][ms][r] + b);
        }
        __syncthreads();                   // Ctl ready; Bs[0] reads done
        // V'' frags: 12 chunks, ep-scaled, ep-row at dim'=32 (softmax-l trick)
#pragma unroll
        for (int c = wave; c < 12; c += 4) {
            const int half = c / 6, ch = c % 6;
            const int dt = ch >> 1, kc = ch & 1;
            const int dimp = dt * 16 + i16;
            bf16x8 o;
#pragma unroll
            for (int j = 0; j < 8; ++j) {
                const int key = half * 64 + kc * 32 + quad * 8 + j; // local
                float v;
                if (dimp < 32)       v = (float)Ctl[key * 36 + dimp] * eps[key];
                else if (dimp == 32) v = eps[key];
                else                 v = 0.f;
                o[j] = (bf16)v;
            }
            *(bf16x8*)&Vf[((size_t)(g * 64 + mb * 2 + half) * 6 + ch) * 512 + lane * 8] = o;
        }
    }
}

// ---------------------------------------------------------------------------
// Staged 3-term split-bf16 GEMM — out proj (round-4 structure, proven).
// NTILE=16, grid (32,16) = 512 blocks (2/CU), two accumulator chains.
// Round-7: B panel cast INLINE from fp32 Wout (same bytes staged: 16 KB fp32
// vs 16 KB hi+lo bf16; identical v->hi, v-hi->lo expressions -> bit-identical)
// — removes the Wout piggyback phase from gemmqkv's critical-path tail.
// ---------------------------------------------------------------------------
template <int NOUT, int NTILE, typename OT>
__global__ __launch_bounds__(256, 2) void gemm3s_kernel(const bf16* __restrict__ Ah,
                                                        const bf16* __restrict__ Al,
                                                        const float* __restrict__ Wout,
                                                        const float* __restrict__ bias,
                                                        OT* __restrict__ C) {
    constexpr int NS = NTILE / 16;
    const int t = threadIdx.x, wave = t >> 6, lane = t & 63;
    const int quad = lane >> 4, i16 = lane & 15;
    const int m0 = blockIdx.x * 128 + wave * 32;
    const int n0 = blockIdx.y * NTILE;

    __shared__ __align__(16) bf16 Bs[NTILE * 512];

    {   // stage B panel with inline hi/lo cast from fp32 Wout [k][n]
        const int l = t & 63, i16l = l & 15, ql = l >> 4;
#pragma unroll
        for (int cc = t >> 6; cc < NS * 8; cc += 4) {
            const int nsi = cc >> 3, kc = cc & 7;
            const int n = n0 + nsi * 16 + i16l;
            const int kk = kc * 32 + ql * 8;
            bf16x8 h, lo;
#pragma unroll
            for (int j = 0; j < 8; ++j) {
                const float v = Wout[(size_t)(kk + j) * 256 + n];
                const bf16 hh = (bf16)v;
                h[j] = hh;
                lo[j] = (bf16)(v - (float)hh);
            }
            *(bf16x8*)&Bs[cc * 512 + l * 8] = h;
            *(bf16x8*)&Bs[(cc + NS * 8) * 512 + l * 8] = lo;
        }
    }

    bf16x8 ah[2][8], al[2][8];
#pragma unroll
    for (int ms = 0; ms < 2; ++ms) {
        const size_t abase = (size_t)(m0 + ms * 16 + i16) * 256 + quad * 8;
#pragma unroll
        for (int kc = 0; kc < 8; ++kc) {
            ah[ms][kc] = *(const bf16x8*)&Ah[abase + kc * 32];
            al[ms][kc] = *(const bf16x8*)&Al[abase + kc * 32];
        }
    }
    __syncthreads();

#pragma unroll
    for (int nsi = 0; nsi < NS; ++nsi) {
        f32x4 acc[2];
        acc[0] = f32x4{0.f, 0.f, 0.f, 0.f};
        acc[1] = f32x4{0.f, 0.f, 0.f, 0.f};
#pragma unroll
        for (int kc = 0; kc < 8; ++kc) {
            const bf16x8 bh = *(const bf16x8*)&Bs[(nsi * 8 + kc) * 512 + lane * 8];
            const bf16x8 bl = *(const bf16x8*)&Bs[((NS + nsi) * 8 + kc) * 512 + lane * 8];
            acc[0] = MFMA(ah[0][kc], bh, acc[0]);
            acc[0] = MFMA(ah[0][kc], bl, acc[0]);
            acc[0] = MFMA(al[0][kc], bh, acc[0]);
            acc[1] = MFMA(ah[1][kc], bh, acc[1]);
            acc[1] = MFMA(ah[1][kc], bl, acc[1]);
            acc[1] = MFMA(al[1][kc], bh, acc[1]);
        }
        const int n = n0 + nsi * 16 + i16;
        const float b = bias[n];
#pragma unroll
        for (int ms = 0; ms < 2; ++ms)
#pragma unroll
            for (int r = 0; r < 4; ++r)
                C[(size_t)(m0 + ms * 16 + quad * 4 + r) * NOUT + n] = (OT)(acc[ms][r] + b);
    }
}

// ---------------------------------------------------------------------------
// Fixed-m flash attention, permlane edition — ROUND-4 EXACT (proven 121.46).
// (512,4): 2 blocks/CU, 4 waves/SIMD.  R6's A/B showed (512,2)+volatile costs
// +6.7 µs: occupancy >> spill cost here.  Do not touch this kernel again.
// ---------------------------------------------------------------------------
__global__ __launch_bounds__(512, 4) void attn_kernel(const bf16* __restrict__ Qb,
                                                      const bf16* __restrict__ Kf,
                                                      const bf16* __restrict__ Vf,
                                                      bf16* __restrict__ aoh,
                                                      bf16* __restrict__ aol) {
    const int t = threadIdx.x, w = t >> 6, lane = t & 63;
    const int quad = lane >> 4, i16 = lane & 15;
    const int qb = blockIdx.y, h = blockIdx.x;

    __shared__ __align__(16) float M[8][2112];   // 67.6 KB epilogue merge

    const int q0 = qb * 64;
    bf16x8 qf[4];
#pragma unroll
    for (int qs = 0; qs < 4; ++qs)
        qf[qs] = *(const bf16x8*)&Qb[(size_t)(q0 + qs * 16 + i16) * 256 + h * 32 + quad * 8];

    f32x4 o[3][4];
#pragma unroll
    for (int dt = 0; dt < 3; ++dt)
#pragma unroll
        for (int qs = 0; qs < 4; ++qs) o[dt][qs] = f32x4{0.f, 0.f, 0.f, 0.f};

    const bf16* kb = Kf + (size_t)(h * 64) * 2048 + lane * 8;
    const bf16* vb = Vf + (size_t)(h * 64) * 3072 + lane * 8;

    const int kt0 = w * 8;
    for (int it = 0; it < 8; ++it) {
        const int kt = kt0 + it;
        bf16x8 kcur[4];
#pragma unroll
        for (int s = 0; s < 4; ++s)
            kcur[s] = *(const bf16x8*)&kb[((size_t)kt * 4 + s) * 512];

        const f32x4 z = {0.f, 0.f, 0.f, 0.f};
        u32x4 P[4][2];   // [qs][32-key half] -> PV B-frag words (all static idx)
#pragma unroll
        for (int qh = 0; qh < 2; ++qh) {
            f32x4 sf[2][4];
#pragma unroll
            for (int ks = 0; ks < 4; ++ks) {
                sf[0][ks] = MFMA(kcur[ks], qf[qh * 2 + 0], z);
                sf[1][ks] = MFMA(kcur[ks], qf[qh * 2 + 1], z);
            }
#pragma unroll
            for (int qi = 0; qi < 2; ++qi) {
                const int qs = qh * 2 + qi;
#pragma unroll
                for (int h2 = 0; h2 < 2; ++h2) {
                    const f32x4 s0 = sf[qi][2 * h2 + 0];
                    const f32x4 s1 = sf[qi][2 * h2 + 1];
                    u32 a = pkbf(__builtin_amdgcn_exp2f(s0[0]),
                                 __builtin_amdgcn_exp2f(s0[1]));
                    u32 b = pkbf(__builtin_amdgcn_exp2f(s0[2]),
                                 __builtin_amdgcn_exp2f(s0[3]));
                    u32 c = pkbf(__builtin_amdgcn_exp2f(s1[0]),
                                 __builtin_amdgcn_exp2f(s1[1]));
                    u32 d = pkbf(__builtin_amdgcn_exp2f(s1[2]),
                                 __builtin_amdgcn_exp2f(s1[3]));
                    asm("v_permlane32_swap_b32 %0, %1" : "+v"(a), "+v"(c));
                    asm("v_permlane16_swap_b32 %0, %1" : "+v"(a), "+v"(c));
                    asm("v_permlane32_swap_b32 %0, %1" : "+v"(b), "+v"(d));
                    asm("v_permlane16_swap_b32 %0, %1" : "+v"(b), "+v"(d));
                    P[qs][h2] = u32x4{a, b, c, d};
                }
            }
        }

        bf16x8 vv[6];
#pragma unroll
        for (int c = 0; c < 6; ++c)
            vv[c] = *(const bf16x8*)&vb[((size_t)kt * 6 + c) * 512];

#pragma unroll
        for (int qs = 0; qs < 4; ++qs) {
            const bf16x8 pb0 = __builtin_bit_cast(bf16x8, P[qs][0]);
            const bf16x8 pb1 = __builtin_bit_cast(bf16x8, P[qs][1]);
#pragma unroll
            for (int dt = 0; dt < 3; ++dt) {
                o[dt][qs] = MFMA(vv[dt * 2 + 0], pb0, o[dt][qs]);
                o[dt][qs] = MFMA(vv[dt * 2 + 1], pb1, o[dt][qs]);
            }
        }
    }

    {
        float* myo = &M[w][0];
#pragma unroll
        for (int qs = 0; qs < 4; ++qs) {
            *(f32x4*)&myo[(qs * 64 + lane) * 8 + 0] = o[0][qs];
            *(f32x4*)&myo[(qs * 64 + lane) * 8 + 4] = o[1][qs];
        }
        if (quad == 0) {
#pragma unroll
            for (int qs = 0; qs < 4; ++qs)
                myo[2048 + qs * 16 + i16] = o[2][qs][0];
        }
    }
    __syncthreads();
    if (w < 4) {
        f32x4 a0 = {0.f, 0.f, 0.f, 0.f}, a1 = {0.f, 0.f, 0.f, 0.f};
        float lsum = 0.f;
#pragma unroll
        for (int ww = 0; ww < 8; ++ww) {
            const float* p = &M[ww][0];
            a0 += *(const f32x4*)&p[(w * 64 + lane) * 8 + 0];
            a1 += *(const f32x4*)&p[(w * 64 + lane) * 8 + 4];
            if (lane < 16) lsum += p[2048 + w * 16 + lane];
        }
        const float linv = 1.0f / __shfl(lsum, i16, 64);
        const int row = q0 + w * 16 + i16;
#pragma unroll
        for (int dt = 0; dt < 2; ++dt) {
            const f32x4 src = dt ? a1 : a0;
            bf16x4 hi, lo;
#pragma unroll
            for (int r = 0; r < 4; ++r) {
                const float v = src[r] * linv;
                hi[r] = (bf16)v;
                lo[r] = (bf16)(v - (float)hi[r]);
            }
            const size_t ob = (size_t)row * 256 + h * 32 + dt * 16 + quad * 4;
            *(bf16x4*)&aoh[ob] = hi;
            *(bf16x4*)&aol[ob] = lo;
        }
    }
}

// ---------------------------------------------------------------------------
extern "C" void kernel_launch(void* const* d_in, const int* in_sizes, int n_in,
                              void* d_out, int out_size, void* d_ws, size_t ws_size,
                              hipStream_t stream) {
    const float* x    = (const float*)d_in[0];
    const float* pe   = (const float*)d_in[1];
    const float* Wqkv = (const float*)d_in[2];
    const float* bqkv = (const float*)d_in[3];
    const float* Wpe  = (const float*)d_in[4];
    const float* bpe  = (const float*)d_in[5];
    const float* Wout = (const float*)d_in[6];
    const float* bout = (const float*)d_in[7];
    float* out = (float*)d_out;

    char* ws = (char*)d_ws;
    // first 1 MB intentionally unused (was Wqkv/Wout bf16 buffers; casts inline)
    bf16*  Qb      = (bf16*)(ws + 1048576);         // 2 MB
    bf16*  Kf      = (bf16*)(ws + 3145728);         // 2 MB
    bf16*  Vf      = (bf16*)(ws + 5242880);         // 3 MB
    bf16*  aoh     = (bf16*)(ws + 8388608);         // 2 MB
    bf16*  aol     = (bf16*)(ws + 10485760);        // 2 MB -> 12.6 MB total

    gemmqkv_kernel<<<dim3(32, 8), 256, 0, stream>>>(x, Wqkv, bqkv,
                                                    pe, Wpe, bpe,
                                                    Qb, Kf, Vf);
    attn_kernel<<<dim3(HH, NN / 64), 512, 0, stream>>>(Qb, Kf, Vf, aoh, aol);
    gemm3s_kernel<256, 16, float><<<dim3(32, 16), 256, 0, stream>>>(aoh, aol, Wout, bout, out);
}

// Round 8
// 119.504 us; speedup vs baseline: 1.0723x; 1.0074x over previous
//
#include <hip/hip_runtime.h>
#include <math.h>

#define NN 4096
#define HH 8
constexpr float SCALE = 0.17677669529663687f;   // 1/sqrt(32)
constexpr float LOG2E = 1.4426950408889634f;
constexpr float SC2   = SCALE * LOG2E;          // folded into Q columns of Wqkv

typedef __bf16 bf16;
typedef __bf16 bf16x8 __attribute__((ext_vector_type(8)));
typedef __bf16 bf16x4 __attribute__((ext_vector_type(4)));
typedef __bf16 bf16x2 __attribute__((ext_vector_type(2)));
typedef float  f32x4  __attribute__((ext_vector_type(4)));
typedef unsigned u32;
typedef unsigned u32x4 __attribute__((ext_vector_type(4)));

#define MFMA(a, b, c) __builtin_amdgcn_mfma_f32_16x16x32_bf16((a), (b), (c), 0, 0, 0)

// pack two f32 -> one u32 of 2 bf16 (compiler emits v_cvt_pk_bf16_f32)
__device__ __forceinline__ u32 pkbf(float lo, float hi) {
    bf16x2 t;
    t[0] = (bf16)lo;
    t[1] = (bf16)hi;
    return __builtin_bit_cast(u32, t);
}

// ---------------------------------------------------------------------------
// Fused QKV GEMM, round-8 "2-per-CU" edition.
// R7 ran grid (32,8)=256 blocks = 1 block/CU = 1 wave/SIMD: every barrier-
// separated phase (stage->MFMA->transpose) had its memory waits fully
// exposed.  Now grid (64,8)=512 blocks of 64 tokens = 2 blocks/CU =
// 2 waves/SIMD; each wave owns 16 rows (ms loop gone).  Per-output
// arithmetic (B-cast, A-cast, kc-ordered 3-MFMA chain) is byte-identical.
// ---------------------------------------------------------------------------
__global__ __launch_bounds__(256, 2) void gemmqkv_kernel(
    const float* __restrict__ A, const float* __restrict__ Wqkv,
    const float* __restrict__ bqkv,
    const float* __restrict__ pe, const float* __restrict__ Wpe,
    const float* __restrict__ bpe,
    bf16* __restrict__ Qb, bf16* __restrict__ Kf, bf16* __restrict__ Vf) {
    const int t = threadIdx.x, wave = t >> 6, lane = t & 63;
    const int quad = lane >> 4, i16 = lane & 15;
    const int mb = blockIdx.x, g = blockIdx.y;

    __shared__ __align__(16) bf16 Bs[2][32 * 512];  // 2 x 32 KB B panel (dbuf)
    __shared__ __align__(16) bf16 Ctl[64 * 36];     // 4.5 KB C tile, stride 36
    __shared__ float eps[64];

    const int m0 = mb * 64 + wave * 16;

    // --- B panel staging with inline hi/lo cast (identical math to round 3)
    auto stage_panel = [&](bf16* bs, int ct) {
        const int i16l = lane & 15, ql = lane >> 4;
        const float sc = (ct < 8) ? SC2 : 1.0f;
        const int n0 = ct * 32;
#pragma unroll
        for (int cc = wave; cc < 16; cc += 4) {
            const int nsi = cc >> 3, kc = cc & 7;
            const int n = n0 + nsi * 16 + i16l;
            const int kk = kc * 32 + ql * 8;
            bf16x8 h, l;
#pragma unroll
            for (int j = 0; j < 8; ++j) {
                const float v = Wqkv[(size_t)(kk + j) * 768 + n] * sc;
                const bf16 hh = (bf16)v;
                h[j] = hh;
                l[j] = (bf16)(v - (float)hh);
            }
            *(bf16x8*)&bs[cc * 512 + lane * 8] = h;
            *(bf16x8*)&bs[(cc + 16) * 512 + lane * 8] = l;
        }
    };

    // --- A fragments with inline hi/lo split — 16 rows per wave, once
    bf16x8 ah[8], al[8];
    {
        const int row = m0 + i16;
#pragma unroll
        for (int kc = 0; kc < 8; ++kc) {
            const size_t ab = (size_t)row * 256 + kc * 32 + quad * 8;
            const f32x4 u0 = *(const f32x4*)&A[ab];
            const f32x4 u1 = *(const f32x4*)&A[ab + 4];
#pragma unroll
            for (int e = 0; e < 4; ++e) {
                const bf16 h0 = (bf16)u0[e], h1 = (bf16)u1[e];
                ah[kc][e] = h0;
                ah[kc][e + 4] = h1;
                al[kc][e] = (bf16)(u0[e] - (float)h0);
                al[kc][e + 4] = (bf16)(u1[e] - (float)h1);
            }
        }
    }

    auto run_tile = [&](const bf16* bs, f32x4 (&acc)[2]) {
#pragma unroll
        for (int nsi = 0; nsi < 2; ++nsi) {
            acc[nsi] = f32x4{0.f, 0.f, 0.f, 0.f};
#pragma unroll
            for (int kc = 0; kc < 8; ++kc) {
                const bf16x8 bh = *(const bf16x8*)&bs[(nsi * 8 + kc) * 512 + lane * 8];
                const bf16x8 bl = *(const bf16x8*)&bs[((2 + nsi) * 8 + kc) * 512 + lane * 8];
                acc[nsi] = MFMA(ah[kc], bh, acc[nsi]);
                acc[nsi] = MFMA(ah[kc], bl, acc[nsi]);
                acc[nsi] = MFMA(al[kc], bh, acc[nsi]);
            }
        }
    };

    stage_panel(Bs[0], g);                 // Q panel
    if (t < 64) {    // pe-projection for head g / this token tile (V phase)
        const int n = mb * 64 + t;
        float acc = bpe[g];
#pragma unroll
        for (int k = 0; k < 16; ++k) acc += pe[n * 16 + k] * Wpe[k * 8 + g];
        eps[t] = __builtin_amdgcn_exp2f(-acc * LOG2E - 8.0f);
    }
    __syncthreads();                       // Bs[0] ready

    // ---- Phase Q (ct = g) ----
    stage_panel(Bs[1], 8 + g);             // prefetch K panel
    {
        f32x4 acc[2];
        run_tile(Bs[0], acc);
        const int n0 = g * 32;
#pragma unroll
        for (int nsi = 0; nsi < 2; ++nsi) {
            const int n = n0 + nsi * 16 + i16;
            const float b = bqkv[n] * SC2;
#pragma unroll
            for (int r = 0; r < 4; ++r)
                Qb[(size_t)(m0 + quad * 4 + r) * 256 + n] =
                    (bf16)(acc[nsi][r] + b);
        }
    }
    __syncthreads();                       // Bs[1] ready; Bs[0] reads done

    // ---- Phase K (ct = 8+g, head g) ----
    stage_panel(Bs[0], 16 + g);            // prefetch V panel (Bs[0] free)
    {
        f32x4 acc[2];
        run_tile(Bs[1], acc);
        const int n0 = (8 + g) * 32;
#pragma unroll
        for (int nsi = 0; nsi < 2; ++nsi) {
            const int n = n0 + nsi * 16 + i16;
            const float b = bqkv[n];
#pragma unroll
            for (int r = 0; r < 4; ++r)
                Ctl[(wave * 16 + quad * 4 + r) * 36 + nsi * 16 + i16] =
                    (bf16)(acc[nsi][r] + b);
        }
        __syncthreads();                   // Ctl ready (also: Bs[0] staged)
        // K frags: 4 chunks (4 key-subs), transpose reads; wave w takes s=w
        {
            const int s = wave;
            bf16x8 o;
#pragma unroll
            for (int j = 0; j < 8; ++j)
                o[j] = Ctl[(s * 16 + i16) * 36 + quad * 8 + j];
            *(bf16x8*)&Kf[((size_t)(g * 64 + mb) * 4 + s) * 512 + lane * 8] = o;
        }
    }
    __syncthreads();                       // K-transpose reads of Ctl done

    // ---- Phase V (ct = 16+g, head g) ----
    {
        f32x4 acc[2];
        run_tile(Bs[0], acc);
        const int n0 = (16 + g) * 32;
#pragma unroll
        for (int nsi = 0; nsi < 2; ++nsi) {
            const int n = n0 + nsi * 16 + i16;
            const float b = bqkv[n];
#pragma unroll
            for (int r = 0; r < 4; ++r)
                Ctl[(wave * 16 + quad * 4 + r) * 36 + nsi * 16 + i16] =
                    (bf16)(acc[nsi][r] + b);
        }
        __syncthreads();                   // Ctl ready; Bs[0] reads done
        // V'' frags: 6 chunks (3 d-tiles x 2 key-halves), ep-scaled,
        // ep-row at dim'=32 (softmax-l trick)
#pragma unroll
        for (int c = wave; c < 6; c += 4) {
            const int ch = c;
            const int dt = ch >> 1, kc = ch & 1;
            const int dimp = dt * 16 + i16;
            bf16x8 o;
#pragma unroll
            for (int j = 0; j < 8; ++j) {
                const int key = kc * 32 + quad * 8 + j;   // local row 0..63
                float v;
                if (dimp < 32)       v = (float)Ctl[key * 36 + dimp] * eps[key];
                else if (dimp == 32) v = eps[key];
                else                 v = 0.f;
                o[j] = (bf16)v;
            }
            *(bf16x8*)&Vf[((size_t)(g * 64 + mb) * 6 + ch) * 512 + lane * 8] = o;
        }
    }
}

// ---------------------------------------------------------------------------
// Staged 3-term split-bf16 GEMM — out proj (round-7, proven at 120.39).
// NTILE=16, grid (32,16) = 512 blocks (2/CU), two accumulator chains.
// B panel cast INLINE from fp32 Wout.
// ---------------------------------------------------------------------------
template <int NOUT, int NTILE, typename OT>
__global__ __launch_bounds__(256, 2) void gemm3s_kernel(const bf16* __restrict__ Ah,
                                                        const bf16* __restrict__ Al,
                                                        const float* __restrict__ Wout,
                                                        const float* __restrict__ bias,
                                                        OT* __restrict__ C) {
    constexpr int NS = NTILE / 16;
    const int t = threadIdx.x, wave = t >> 6, lane = t & 63;
    const int quad = lane >> 4, i16 = lane & 15;
    const int m0 = blockIdx.x * 128 + wave * 32;
    const int n0 = blockIdx.y * NTILE;

    __shared__ __align__(16) bf16 Bs[NTILE * 512];

    {   // stage B panel with inline hi/lo cast from fp32 Wout [k][n]
        const int l = t & 63, i16l = l & 15, ql = l >> 4;
#pragma unroll
        for (int cc = t >> 6; cc < NS * 8; cc += 4) {
            const int nsi = cc >> 3, kc = cc & 7;
            const int n = n0 + nsi * 16 + i16l;
            const int kk = kc * 32 + ql * 8;
            bf16x8 h, lo;
#pragma unroll
            for (int j = 0; j < 8; ++j) {
                const float v = Wout[(size_t)(kk + j) * 256 + n];
                const bf16 hh = (bf16)v;
                h[j] = hh;
                lo[j] = (bf16)(v - (float)hh);
            }
            *(bf16x8*)&Bs[cc * 512 + l * 8] = h;
            *(bf16x8*)&Bs[(cc + NS * 8) * 512 + l * 8] = lo;
        }
    }

    bf16x8 ah[2][8], al[2][8];
#pragma unroll
    for (int ms = 0; ms < 2; ++ms) {
        const size_t abase = (size_t)(m0 + ms * 16 + i16) * 256 + quad * 8;
#pragma unroll
        for (int kc = 0; kc < 8; ++kc) {
            ah[ms][kc] = *(const bf16x8*)&Ah[abase + kc * 32];
            al[ms][kc] = *(const bf16x8*)&Al[abase + kc * 32];
        }
    }
    __syncthreads();

#pragma unroll
    for (int nsi = 0; nsi < NS; ++nsi) {
        f32x4 acc[2];
        acc[0] = f32x4{0.f, 0.f, 0.f, 0.f};
        acc[1] = f32x4{0.f, 0.f, 0.f, 0.f};
#pragma unroll
        for (int kc = 0; kc < 8; ++kc) {
            const bf16x8 bh = *(const bf16x8*)&Bs[(nsi * 8 + kc) * 512 + lane * 8];
            const bf16x8 bl = *(const bf16x8*)&Bs[((NS + nsi) * 8 + kc) * 512 + lane * 8];
            acc[0] = MFMA(ah[0][kc], bh, acc[0]);
            acc[0] = MFMA(ah[0][kc], bl, acc[0]);
            acc[0] = MFMA(al[0][kc], bh, acc[0]);
            acc[1] = MFMA(ah[1][kc], bh, acc[1]);
            acc[1] = MFMA(ah[1][kc], bl, acc[1]);
            acc[1] = MFMA(al[1][kc], bh, acc[1]);
        }
        const int n = n0 + nsi * 16 + i16;
        const float b = bias[n];
#pragma unroll
        for (int ms = 0; ms < 2; ++ms)
#pragma unroll
            for (int r = 0; r < 4; ++r)
                C[(size_t)(m0 + ms * 16 + quad * 4 + r) * NOUT + n] = (OT)(acc[ms][r] + b);
    }
}

// ---------------------------------------------------------------------------
// Fixed-m flash attention, permlane edition — ROUND-4 EXACT (proven).
// (512,4): 2 blocks/CU, 4 waves/SIMD.  R6's A/B showed (512,2)+volatile costs
// +6.7 µs: occupancy >> spill cost here.  Do not touch this kernel again.
// ---------------------------------------------------------------------------
__global__ __launch_bounds__(512, 4) void attn_kernel(const bf16* __restrict__ Qb,
                                                      const bf16* __restrict__ Kf,
                                                      const bf16* __restrict__ Vf,
                                                      bf16* __restrict__ aoh,
                                                      bf16* __restrict__ aol) {
    const int t = threadIdx.x, w = t >> 6, lane = t & 63;
    const int quad = lane >> 4, i16 = lane & 15;
    const int qb = blockIdx.y, h = blockIdx.x;

    __shared__ __align__(16) float M[8][2112];   // 67.6 KB epilogue merge

    const int q0 = qb * 64;
    bf16x8 qf[4];
#pragma unroll
    for (int qs = 0; qs < 4; ++qs)
        qf[qs] = *(const bf16x8*)&Qb[(size_t)(q0 + qs * 16 + i16) * 256 + h * 32 + quad * 8];

    f32x4 o[3][4];
#pragma unroll
    for (int dt = 0; dt < 3; ++dt)
#pragma unroll
        for (int qs = 0; qs < 4; ++qs) o[dt][qs] = f32x4{0.f, 0.f, 0.f, 0.f};

    const bf16* kb = Kf + (size_t)(h * 64) * 2048 + lane * 8;
    const bf16* vb = Vf + (size_t)(h * 64) * 3072 + lane * 8;

    const int kt0 = w * 8;
    for (int it = 0; it < 8; ++it) {
        const int kt = kt0 + it;
        bf16x8 kcur[4];
#pragma unroll
        for (int s = 0; s < 4; ++s)
            kcur[s] = *(const bf16x8*)&kb[((size_t)kt * 4 + s) * 512];

        const f32x4 z = {0.f, 0.f, 0.f, 0.f};
        u32x4 P[4][2];   // [qs][32-key half] -> PV B-frag words (all static idx)
#pragma unroll
        for (int qh = 0; qh < 2; ++qh) {
            f32x4 sf[2][4];
#pragma unroll
            for (int ks = 0; ks < 4; ++ks) {
                sf[0][ks] = MFMA(kcur[ks], qf[qh * 2 + 0], z);
                sf[1][ks] = MFMA(kcur[ks], qf[qh * 2 + 1], z);
            }
#pragma unroll
            for (int qi = 0; qi < 2; ++qi) {
                const int qs = qh * 2 + qi;
#pragma unroll
                for (int h2 = 0; h2 < 2; ++h2) {
                    const f32x4 s0 = sf[qi][2 * h2 + 0];
                    const f32x4 s1 = sf[qi][2 * h2 + 1];
                    u32 a = pkbf(__builtin_amdgcn_exp2f(s0[0]),
                                 __builtin_amdgcn_exp2f(s0[1]));
                    u32 b = pkbf(__builtin_amdgcn_exp2f(s0[2]),
                                 __builtin_amdgcn_exp2f(s0[3]));
                    u32 c = pkbf(__builtin_amdgcn_exp2f(s1[0]),
                                 __builtin_amdgcn_exp2f(s1[1]));
                    u32 d = pkbf(__builtin_amdgcn_exp2f(s1[2]),
                                 __builtin_amdgcn_exp2f(s1[3]));
                    asm("v_permlane32_swap_b32 %0, %1" : "+v"(a), "+v"(c));
                    asm("v_permlane16_swap_b32 %0, %1" : "+v"(a), "+v"(c));
                    asm("v_permlane32_swap_b32 %0, %1" : "+v"(b), "+v"(d));
                    asm("v_permlane16_swap_b32 %0, %1" : "+v"(b), "+v"(d));
                    P[qs][h2] = u32x4{a, b, c, d};
                }
            }
        }

        bf16x8 vv[6];
#pragma unroll
        for (int c = 0; c < 6; ++c)
            vv[c] = *(const bf16x8*)&vb[((size_t)kt * 6 + c) * 512];

#pragma unroll
        for (int qs = 0; qs < 4; ++qs) {
            const bf16x8 pb0 = __builtin_bit_cast(bf16x8, P[qs][0]);
            const bf16x8 pb1 = __builtin_bit_cast(bf16x8, P[qs][1]);
#pragma unroll
            for (int dt = 0; dt < 3; ++dt) {
                o[dt][qs] = MFMA(vv[dt * 2 + 0], pb0, o[dt][qs]);
                o[dt][qs] = MFMA(vv[dt * 2 + 1], pb1, o[dt][qs]);
            }
        }
    }

    {
        float* myo = &M[w][0];
#pragma unroll
        for (int qs = 0; qs < 4; ++qs) {
            *(f32x4*)&myo[(qs * 64 + lane) * 8 + 0] = o[0][qs];
            *(f32x4*)&myo[(qs * 64 + lane) * 8 + 4] = o[1][qs];
        }
        if (quad == 0) {
#pragma unroll
            for (int qs = 0; qs < 4; ++qs)
                myo[2048 + qs * 16 + i16] = o[2][qs][0];
        }
    }
    __syncthreads();
    if (w < 4) {
        f32x4 a0 = {0.f, 0.f, 0.f, 0.f}, a1 = {0.f, 0.f, 0.f, 0.f};
        float lsum = 0.f;
#pragma unroll
        for (int ww = 0; ww < 8; ++ww) {
            const float* p = &M[ww][0];
            a0 += *(const f32x4*)&p[(w * 64 + lane) * 8 + 0];
            a1 += *(const f32x4*)&p[(w * 64 + lane) * 8 + 4];
            if (lane < 16) lsum += p[2048 + w * 16 + lane];
        }
        const float linv = 1.0f / __shfl(lsum, i16, 64);
        const int row = q0 + w * 16 + i16;
#pragma unroll
        for (int dt = 0; dt < 2; ++dt) {
            const f32x4 src = dt ? a1 : a0;
            bf16x4 hi, lo;
#pragma unroll
            for (int r = 0; r < 4; ++r) {
                const float v = src[r] * linv;
                hi[r] = (bf16)v;
                lo[r] = (bf16)(v - (float)hi[r]);
            }
            const size_t ob = (size_t)row * 256 + h * 32 + dt * 16 + quad * 4;
            *(bf16x4*)&aoh[ob] = hi;
            *(bf16x4*)&aol[ob] = lo;
        }
    }
}

// ---------------------------------------------------------------------------
extern "C" void kernel_launch(void* const* d_in, const int* in_sizes, int n_in,
                              void* d_out, int out_size, void* d_ws, size_t ws_size,
                              hipStream_t stream) {
    const float* x    = (const float*)d_in[0];
    const float* pe   = (const float*)d_in[1];
    const float* Wqkv = (const float*)d_in[2];
    const float* bqkv = (const float*)d_in[3];
    const float* Wpe  = (const float*)d_in[4];
    const float* bpe  = (const float*)d_in[5];
    const float* Wout = (const float*)d_in[6];
    const float* bout = (const float*)d_in[7];
    float* out = (float*)d_out;

    char* ws = (char*)d_ws;
    // first 1 MB intentionally unused (was Wqkv/Wout bf16 buffers; casts inline)
    bf16*  Qb      = (bf16*)(ws + 1048576);         // 2 MB
    bf16*  Kf      = (bf16*)(ws + 3145728);         // 2 MB
    bf16*  Vf      = (bf16*)(ws + 5242880);         // 3 MB
    bf16*  aoh     = (bf16*)(ws + 8388608);         // 2 MB
    bf16*  aol     = (bf16*)(ws + 10485760);        // 2 MB -> 12.6 MB total

    gemmqkv_kernel<<<dim3(64, 8), 256, 0, stream>>>(x, Wqkv, bqkv,
                                                    pe, Wpe, bpe,
                                                    Qb, Kf, Vf);
    attn_kernel<<<dim3(HH, NN / 64), 512, 0, stream>>>(Qb, Kf, Vf, aoh, aol);
    gemm3s_kernel<256, 16, float><<<dim3(32, 16), 256, 0, stream>>>(aoh, aol, Wout, bout, out);
}

// Round 10
// 117.042 us; speedup vs baseline: 1.0949x; 1.0210x over previous
//
#include <hip/hip_runtime.h>
#include <math.h>

#define NN 4096
#define HH 8
constexpr float SCALE = 0.17677669529663687f;   // 1/sqrt(32)
constexpr float LOG2E = 1.4426950408889634f;
constexpr float SC2   = SCALE * LOG2E;          // folded into Q columns of Wqkv

typedef __bf16 bf16;
typedef __bf16 bf16x8 __attribute__((ext_vector_type(8)));
typedef __bf16 bf16x4 __attribute__((ext_vector_type(4)));
typedef __bf16 bf16x2 __attribute__((ext_vector_type(2)));
typedef float  f32x4  __attribute__((ext_vector_type(4)));
typedef unsigned u32;
typedef unsigned u32x4 __attribute__((ext_vector_type(4)));

#define MFMA(a, b, c) __builtin_amdgcn_mfma_f32_16x16x32_bf16((a), (b), (c), 0, 0, 0)

// pack two f32 -> one u32 of 2 bf16 (compiler emits v_cvt_pk_bf16_f32)
__device__ __forceinline__ u32 pkbf(float lo, float hi) {
    bf16x2 t;
    t[0] = (bf16)lo;
    t[1] = (bf16)hi;
    return __builtin_bit_cast(u32, t);
}

// ---------------------------------------------------------------------------
// Fused QKV GEMM, round-8 "2-per-CU" edition (proven at 119.50) — UNCHANGED.
// Grid (64,8)=512 blocks of 64 tokens = 2 blocks/CU; each wave owns 16 rows.
// NOTE (R9): cooperative attn+gemm3s fusion FAILED with stale cross-XCD reads
// (absmax 0.139) — per-XCD L2 write-back lines were not visible to consumer
// XCDs under a t0 threadfence+agent-atomic spin protocol.  Fusion track closed.
// ---------------------------------------------------------------------------
__global__ __launch_bounds__(256, 2) void gemmqkv_kernel(
    const float* __restrict__ A, const float* __restrict__ Wqkv,
    const float* __restrict__ bqkv,
    const float* __restrict__ pe, const float* __restrict__ Wpe,
    const float* __restrict__ bpe,
    bf16* __restrict__ Qb, bf16* __restrict__ Kf, bf16* __restrict__ Vf) {
    const int t = threadIdx.x, wave = t >> 6, lane = t & 63;
    const int quad = lane >> 4, i16 = lane & 15;
    const int mb = blockIdx.x, g = blockIdx.y;

    __shared__ __align__(16) bf16 Bs[2][32 * 512];  // 2 x 32 KB B panel (dbuf)
    __shared__ __align__(16) bf16 Ctl[64 * 36];     // 4.5 KB C tile, stride 36
    __shared__ float eps[64];

    const int m0 = mb * 64 + wave * 16;

    // --- B panel staging with inline hi/lo cast (identical math to round 3)
    auto stage_panel = [&](bf16* bs, int ct) {
        const int i16l = lane & 15, ql = lane >> 4;
        const float sc = (ct < 8) ? SC2 : 1.0f;
        const int n0 = ct * 32;
#pragma unroll
        for (int cc = wave; cc < 16; cc += 4) {
            const int nsi = cc >> 3, kc = cc & 7;
            const int n = n0 + nsi * 16 + i16l;
            const int kk = kc * 32 + ql * 8;
            bf16x8 h, l;
#pragma unroll
            for (int j = 0; j < 8; ++j) {
                const float v = Wqkv[(size_t)(kk + j) * 768 + n] * sc;
                const bf16 hh = (bf16)v;
                h[j] = hh;
                l[j] = (bf16)(v - (float)hh);
            }
            *(bf16x8*)&bs[cc * 512 + lane * 8] = h;
            *(bf16x8*)&bs[(cc + 16) * 512 + lane * 8] = l;
        }
    };

    // --- A fragments with inline hi/lo split — 16 rows per wave, once
    bf16x8 ah[8], al[8];
    {
        const int row = m0 + i16;
#pragma unroll
        for (int kc = 0; kc < 8; ++kc) {
            const size_t ab = (size_t)row * 256 + kc * 32 + quad * 8;
            const f32x4 u0 = *(const f32x4*)&A[ab];
            const f32x4 u1 = *(const f32x4*)&A[ab + 4];
#pragma unroll
            for (int e = 0; e < 4; ++e) {
                const bf16 h0 = (bf16)u0[e], h1 = (bf16)u1[e];
                ah[kc][e] = h0;
                ah[kc][e + 4] = h1;
                al[kc][e] = (bf16)(u0[e] - (float)h0);
                al[kc][e + 4] = (bf16)(u1[e] - (float)h1);
            }
        }
    }

    auto run_tile = [&](const bf16* bs, f32x4 (&acc)[2]) {
#pragma unroll
        for (int nsi = 0; nsi < 2; ++nsi) {
            acc[nsi] = f32x4{0.f, 0.f, 0.f, 0.f};
#pragma unroll
            for (int kc = 0; kc < 8; ++kc) {
                const bf16x8 bh = *(const bf16x8*)&bs[(nsi * 8 + kc) * 512 + lane * 8];
                const bf16x8 bl = *(const bf16x8*)&bs[((2 + nsi) * 8 + kc) * 512 + lane * 8];
                acc[nsi] = MFMA(ah[kc], bh, acc[nsi]);
                acc[nsi] = MFMA(ah[kc], bl, acc[nsi]);
                acc[nsi] = MFMA(al[kc], bh, acc[nsi]);
            }
        }
    };

    stage_panel(Bs[0], g);                 // Q panel
    if (t < 64) {    // pe-projection for head g / this token tile (V phase)
        const int n = mb * 64 + t;
        float acc = bpe[g];
#pragma unroll
        for (int k = 0; k < 16; ++k) acc += pe[n * 16 + k] * Wpe[k * 8 + g];
        eps[t] = __builtin_amdgcn_exp2f(-acc * LOG2E - 8.0f);
    }
    __syncthreads();                       // Bs[0] ready

    // ---- Phase Q (ct = g) ----
    stage_panel(Bs[1], 8 + g);             // prefetch K panel
    {
        f32x4 acc[2];
        run_tile(Bs[0], acc);
        const int n0 = g * 32;
#pragma unroll
        for (int nsi = 0; nsi < 2; ++nsi) {
            const int n = n0 + nsi * 16 + i16;
            const float b = bqkv[n] * SC2;
#pragma unroll
            for (int r = 0; r < 4; ++r)
                Qb[(size_t)(m0 + quad * 4 + r) * 256 + n] =
                    (bf16)(acc[nsi][r] + b);
        }
    }
    __syncthreads();                       // Bs[1] ready; Bs[0] reads done

    // ---- Phase K (ct = 8+g, head g) ----
    stage_panel(Bs[0], 16 + g);            // prefetch V panel (Bs[0] free)
    {
        f32x4 acc[2];
        run_tile(Bs[1], acc);
        const int n0 = (8 + g) * 32;
#pragma unroll
        for (int nsi = 0; nsi < 2; ++nsi) {
            const int n = n0 + nsi * 16 + i16;
            const float b = bqkv[n];
#pragma unroll
            for (int r = 0; r < 4; ++r)
                Ctl[(wave * 16 + quad * 4 + r) * 36 + nsi * 16 + i16] =
                    (bf16)(acc[nsi][r] + b);
        }
        __syncthreads();                   // Ctl ready (also: Bs[0] staged)
        // K frags: 4 chunks (4 key-subs), transpose reads; wave w takes s=w
        {
            const int s = wave;
            bf16x8 o;
#pragma unroll
            for (int j = 0; j < 8; ++j)
                o[j] = Ctl[(s * 16 + i16) * 36 + quad * 8 + j];
            *(bf16x8*)&Kf[((size_t)(g * 64 + mb) * 4 + s) * 512 + lane * 8] = o;
        }
    }
    __syncthreads();                       // K-transpose reads of Ctl done

    // ---- Phase V (ct = 16+g, head g) ----
    {
        f32x4 acc[2];
        run_tile(Bs[0], acc);
        const int n0 = (16 + g) * 32;
#pragma unroll
        for (int nsi = 0; nsi < 2; ++nsi) {
            const int n = n0 + nsi * 16 + i16;
            const float b = bqkv[n];
#pragma unroll
            for (int r = 0; r < 4; ++r)
                Ctl[(wave * 16 + quad * 4 + r) * 36 + nsi * 16 + i16] =
                    (bf16)(acc[nsi][r] + b);
        }
        __syncthreads();                   // Ctl ready; Bs[0] reads done
        // V'' frags: 6 chunks (3 d-tiles x 2 key-halves), ep-scaled,
        // ep-row at dim'=32 (softmax-l trick)
#pragma unroll
        for (int c = wave; c < 6; c += 4) {
            const int ch = c;
            const int dt = ch >> 1, kc = ch & 1;
            const int dimp = dt * 16 + i16;
            bf16x8 o;
#pragma unroll
            for (int j = 0; j < 8; ++j) {
                const int key = kc * 32 + quad * 8 + j;   // local row 0..63
                float v;
                if (dimp < 32)       v = (float)Ctl[key * 36 + dimp] * eps[key];
                else if (dimp == 32) v = eps[key];
                else                 v = 0.f;
                o[j] = (bf16)v;
            }
            *(bf16x8*)&Vf[((size_t)(g * 64 + mb) * 6 + ch) * 512 + lane * 8] = o;
        }
    }
}

// ---------------------------------------------------------------------------
// Staged 3-term split-bf16 GEMM — out proj.  Round-10 retile: grid (64,8),
// NTILE=32, 64-row m-panels (1 ms per wave), TWO accumulator chains
// interleaved at MFMA granularity (kc-outer, nsi-inner) — unlike R5's
// regression this keeps 2 blocks/CU AND dual chains.  A-operand L2 traffic
// halves (64->32 MB), A-frag VGPRs halve; B-cast doubles (+8 MB).  Per-output
// kc-order and operand order unchanged -> bit-identical results.
// ---------------------------------------------------------------------------
template <int NOUT, typename OT>
__global__ __launch_bounds__(256, 2) void gemm3s_kernel(const bf16* __restrict__ Ah,
                                                        const bf16* __restrict__ Al,
                                                        const float* __restrict__ Wout,
                                                        const float* __restrict__ bias,
                                                        OT* __restrict__ C) {
    const int t = threadIdx.x, wave = t >> 6, lane = t & 63;
    const int quad = lane >> 4, i16 = lane & 15;
    const int m0 = blockIdx.x * 64 + wave * 16;
    const int n0 = blockIdx.y * 32;

    __shared__ __align__(16) bf16 Bs[32 * 512];   // 32 KB

    {   // stage B panel with inline hi/lo cast from fp32 Wout [k][n]
        const int i16l = lane & 15, ql = lane >> 4;
#pragma unroll
        for (int cc = wave; cc < 16; cc += 4) {
            const int nsi = cc >> 3, kc = cc & 7;
            const int n = n0 + nsi * 16 + i16l;
            const int kk = kc * 32 + ql * 8;
            bf16x8 h, lo;
#pragma unroll
            for (int j = 0; j < 8; ++j) {
                const float v = Wout[(size_t)(kk + j) * 256 + n];
                const bf16 hh = (bf16)v;
                h[j] = hh;
                lo[j] = (bf16)(v - (float)hh);
            }
            *(bf16x8*)&Bs[cc * 512 + lane * 8] = h;
            *(bf16x8*)&Bs[(cc + 16) * 512 + lane * 8] = lo;
        }
    }

    bf16x8 ah[8], al[8];
    {
        const size_t abase = (size_t)(m0 + i16) * 256 + quad * 8;
#pragma unroll
        for (int kc = 0; kc < 8; ++kc) {
            ah[kc] = *(const bf16x8*)&Ah[abase + kc * 32];
            al[kc] = *(const bf16x8*)&Al[abase + kc * 32];
        }
    }
    __syncthreads();

    f32x4 acc[2];
    acc[0] = f32x4{0.f, 0.f, 0.f, 0.f};
    acc[1] = f32x4{0.f, 0.f, 0.f, 0.f};
#pragma unroll
    for (int kc = 0; kc < 8; ++kc) {
#pragma unroll
        for (int nsi = 0; nsi < 2; ++nsi) {
            const bf16x8 bh = *(const bf16x8*)&Bs[(nsi * 8 + kc) * 512 + lane * 8];
            const bf16x8 bl = *(const bf16x8*)&Bs[((2 + nsi) * 8 + kc) * 512 + lane * 8];
            acc[nsi] = MFMA(ah[kc], bh, acc[nsi]);
            acc[nsi] = MFMA(ah[kc], bl, acc[nsi]);
            acc[nsi] = MFMA(al[kc], bh, acc[nsi]);
        }
    }
#pragma unroll
    for (int nsi = 0; nsi < 2; ++nsi) {
        const int n = n0 + nsi * 16 + i16;
        const float b = bias[n];
#pragma unroll
        for (int r = 0; r < 4; ++r)
            C[(size_t)(m0 + quad * 4 + r) * NOUT + n] = (OT)(acc[nsi][r] + b);
    }
}

// ---------------------------------------------------------------------------
// Fixed-m flash attention, permlane edition.  Main loop = ROUND-4 EXACT
// (frozen: (512,4), non-volatile permlanes).  Round-10 touches ONLY the
// epilogue: 8-wave merge split — wave w handles row-group (w&3) and
// column-half (w>>2), one f32x4 per lane instead of two; waves 4-7 no longer
// idle.  Same ww-ordered additions per output -> bit-identical numerics.
// ---------------------------------------------------------------------------
__global__ __launch_bounds__(512, 4) void attn_kernel(const bf16* __restrict__ Qb,
                                                      const bf16* __restrict__ Kf,
                                                      const bf16* __restrict__ Vf,
                                                      bf16* __restrict__ aoh,
                                                      bf16* __restrict__ aol) {
    const int t = threadIdx.x, w = t >> 6, lane = t & 63;
    const int quad = lane >> 4, i16 = lane & 15;
    const int qb = blockIdx.y, h = blockIdx.x;

    __shared__ __align__(16) float M[8][2112];   // 67.6 KB epilogue merge

    const int q0 = qb * 64;
    bf16x8 qf[4];
#pragma unroll
    for (int qs = 0; qs < 4; ++qs)
        qf[qs] = *(const bf16x8*)&Qb[(size_t)(q0 + qs * 16 + i16) * 256 + h * 32 + quad * 8];

    f32x4 o[3][4];
#pragma unroll
    for (int dt = 0; dt < 3; ++dt)
#pragma unroll
        for (int qs = 0; qs < 4; ++qs) o[dt][qs] = f32x4{0.f, 0.f, 0.f, 0.f};

    const bf16* kb = Kf + (size_t)(h * 64) * 2048 + lane * 8;
    const bf16* vb = Vf + (size_t)(h * 64) * 3072 + lane * 8;

    const int kt0 = w * 8;
    for (int it = 0; it < 8; ++it) {
        const int kt = kt0 + it;
        bf16x8 kcur[4];
#pragma unroll
        for (int s = 0; s < 4; ++s)
            kcur[s] = *(const bf16x8*)&kb[((size_t)kt * 4 + s) * 512];

        const f32x4 z = {0.f, 0.f, 0.f, 0.f};
        u32x4 P[4][2];   // [qs][32-key half] -> PV B-frag words (all static idx)
#pragma unroll
        for (int qh = 0; qh < 2; ++qh) {
            f32x4 sf[2][4];
#pragma unroll
            for (int ks = 0; ks < 4; ++ks) {
                sf[0][ks] = MFMA(kcur[ks], qf[qh * 2 + 0], z);
                sf[1][ks] = MFMA(kcur[ks], qf[qh * 2 + 1], z);
            }
#pragma unroll
            for (int qi = 0; qi < 2; ++qi) {
                const int qs = qh * 2 + qi;
#pragma unroll
                for (int h2 = 0; h2 < 2; ++h2) {
                    const f32x4 s0 = sf[qi][2 * h2 + 0];
                    const f32x4 s1 = sf[qi][2 * h2 + 1];
                    u32 a = pkbf(__builtin_amdgcn_exp2f(s0[0]),
                                 __builtin_amdgcn_exp2f(s0[1]));
                    u32 b = pkbf(__builtin_amdgcn_exp2f(s0[2]),
                                 __builtin_amdgcn_exp2f(s0[3]));
                    u32 c = pkbf(__builtin_amdgcn_exp2f(s1[0]),
                                 __builtin_amdgcn_exp2f(s1[1]));
                    u32 d = pkbf(__builtin_amdgcn_exp2f(s1[2]),
                                 __builtin_amdgcn_exp2f(s1[3]));
                    asm("v_permlane32_swap_b32 %0, %1" : "+v"(a), "+v"(c));
                    asm("v_permlane16_swap_b32 %0, %1" : "+v"(a), "+v"(c));
                    asm("v_permlane32_swap_b32 %0, %1" : "+v"(b), "+v"(d));
                    asm("v_permlane16_swap_b32 %0, %1" : "+v"(b), "+v"(d));
                    P[qs][h2] = u32x4{a, b, c, d};
                }
            }
        }

        bf16x8 vv[6];
#pragma unroll
        for (int c = 0; c < 6; ++c)
            vv[c] = *(const bf16x8*)&vb[((size_t)kt * 6 + c) * 512];

#pragma unroll
        for (int qs = 0; qs < 4; ++qs) {
            const bf16x8 pb0 = __builtin_bit_cast(bf16x8, P[qs][0]);
            const bf16x8 pb1 = __builtin_bit_cast(bf16x8, P[qs][1]);
#pragma unroll
            for (int dt = 0; dt < 3; ++dt) {
                o[dt][qs] = MFMA(vv[dt * 2 + 0], pb0, o[dt][qs]);
                o[dt][qs] = MFMA(vv[dt * 2 + 1], pb1, o[dt][qs]);
            }
        }
    }

    {
        float* myo = &M[w][0];
#pragma unroll
        for (int qs = 0; qs < 4; ++qs) {
            *(f32x4*)&myo[(qs * 64 + lane) * 8 + 0] = o[0][qs];
            *(f32x4*)&myo[(qs * 64 + lane) * 8 + 4] = o[1][qs];
        }
        if (quad == 0) {
#pragma unroll
            for (int qs = 0; qs < 4; ++qs)
                myo[2048 + qs * 16 + i16] = o[2][qs][0];
        }
    }
    __syncthreads();
    {
        const int rg = w & 3, cs = w >> 2;   // row-group, column-half
        f32x4 a = {0.f, 0.f, 0.f, 0.f};
        float lsum = 0.f;
#pragma unroll
        for (int ww = 0; ww < 8; ++ww) {
            const float* p = &M[ww][0];
            a += *(const f32x4*)&p[(rg * 64 + lane) * 8 + cs * 4];
            if (lane < 16) lsum += p[2048 + rg * 16 + lane];
        }
        const float linv = 1.0f / __shfl(lsum, i16, 64);
        const int row = q0 + rg * 16 + i16;
        bf16x4 hi, lo;
#pragma unroll
        for (int r = 0; r < 4; ++r) {
            const float v = a[r] * linv;
            hi[r] = (bf16)v;
            lo[r] = (bf16)(v - (float)hi[r]);
        }
        const size_t ob = (size_t)row * 256 + h * 32 + cs * 16 + quad * 4;
        *(bf16x4*)&aoh[ob] = hi;
        *(bf16x4*)&aol[ob] = lo;
    }
}

// ---------------------------------------------------------------------------
extern "C" void kernel_launch(void* const* d_in, const int* in_sizes, int n_in,
                              void* d_out, int out_size, void* d_ws, size_t ws_size,
                              hipStream_t stream) {
    const float* x    = (const float*)d_in[0];
    const float* pe   = (const float*)d_in[1];
    const float* Wqkv = (const float*)d_in[2];
    const float* bqkv = (const float*)d_in[3];
    const float* Wpe  = (const float*)d_in[4];
    const float* bpe  = (const float*)d_in[5];
    const float* Wout = (const float*)d_in[6];
    const float* bout = (const float*)d_in[7];
    float* out = (float*)d_out;

    char* ws = (char*)d_ws;
    // first 1 MB intentionally unused (was Wqkv/Wout bf16 buffers; casts inline)
    bf16*  Qb      = (bf16*)(ws + 1048576);         // 2 MB
    bf16*  Kf      = (bf16*)(ws + 3145728);         // 2 MB
    bf16*  Vf      = (bf16*)(ws + 5242880);         // 3 MB
    bf16*  aoh     = (bf16*)(ws + 8388608);         // 2 MB
    bf16*  aol     = (bf16*)(ws + 10485760);        // 2 MB -> 12.6 MB total

    gemmqkv_kernel<<<dim3(64, 8), 256, 0, stream>>>(x, Wqkv, bqkv,
                                                    pe, Wpe, bpe,
                                                    Qb, Kf, Vf);
    attn_kernel<<<dim3(HH, NN / 64), 512, 0, stream>>>(Qb, Kf, Vf, aoh, aol);
    gemm3s_kernel<256, float><<<dim3(64, 8), 256, 0, stream>>>(aoh, aol, Wout, bout, out);
}

// Round 11
// 116.427 us; speedup vs baseline: 1.1007x; 1.0053x over previous
//
#include <hip/hip_runtime.h>
#include <math.h>

#define NN 4096
#define HH 8
constexpr float SCALE = 0.17677669529663687f;   // 1/sqrt(32)
constexpr float LOG2E = 1.4426950408889634f;
constexpr float SC2   = SCALE * LOG2E;          // folded into Q columns of Wqkv

typedef __bf16 bf16;
typedef __bf16 bf16x8 __attribute__((ext_vector_type(8)));
typedef __bf16 bf16x4 __attribute__((ext_vector_type(4)));
typedef __bf16 bf16x2 __attribute__((ext_vector_type(2)));
typedef float  f32x4  __attribute__((ext_vector_type(4)));
typedef unsigned u32;
typedef unsigned u32x4 __attribute__((ext_vector_type(4)));

#define MFMA(a, b, c) __builtin_amdgcn_mfma_f32_16x16x32_bf16((a), (b), (c), 0, 0, 0)

// pack two f32 -> one u32 of 2 bf16 (compiler emits v_cvt_pk_bf16_f32)
__device__ __forceinline__ u32 pkbf(float lo, float hi) {
    bf16x2 t;
    t[0] = (bf16)lo;
    t[1] = (bf16)hi;
    return __builtin_bit_cast(u32, t);
}

// ---------------------------------------------------------------------------
// Fused QKV GEMM, round-8 "2-per-CU" edition (proven) — UNCHANGED.
// Grid (64,8)=512 blocks of 64 tokens = 2 blocks/CU; each wave owns 16 rows.
// NOTE (R9): cooperative attn+gemm3s fusion FAILED: re-poison fill leaves
// stale aoh/aol lines in every XCD's L2; producer-side release cannot evict
// consumer-XCD copies from source level.  Fusion track permanently closed.
// ---------------------------------------------------------------------------
__global__ __launch_bounds__(256, 2) void gemmqkv_kernel(
    const float* __restrict__ A, const float* __restrict__ Wqkv,
    const float* __restrict__ bqkv,
    const float* __restrict__ pe, const float* __restrict__ Wpe,
    const float* __restrict__ bpe,
    bf16* __restrict__ Qb, bf16* __restrict__ Kf, bf16* __restrict__ Vf) {
    const int t = threadIdx.x, wave = t >> 6, lane = t & 63;
    const int quad = lane >> 4, i16 = lane & 15;
    const int mb = blockIdx.x, g = blockIdx.y;

    __shared__ __align__(16) bf16 Bs[2][32 * 512];  // 2 x 32 KB B panel (dbuf)
    __shared__ __align__(16) bf16 Ctl[64 * 36];     // 4.5 KB C tile, stride 36
    __shared__ float eps[64];

    const int m0 = mb * 64 + wave * 16;

    // --- B panel staging with inline hi/lo cast (identical math to round 3)
    auto stage_panel = [&](bf16* bs, int ct) {
        const int i16l = lane & 15, ql = lane >> 4;
        const float sc = (ct < 8) ? SC2 : 1.0f;
        const int n0 = ct * 32;
#pragma unroll
        for (int cc = wave; cc < 16; cc += 4) {
            const int nsi = cc >> 3, kc = cc & 7;
            const int n = n0 + nsi * 16 + i16l;
            const int kk = kc * 32 + ql * 8;
            bf16x8 h, l;
#pragma unroll
            for (int j = 0; j < 8; ++j) {
                const float v = Wqkv[(size_t)(kk + j) * 768 + n] * sc;
                const bf16 hh = (bf16)v;
                h[j] = hh;
                l[j] = (bf16)(v - (float)hh);
            }
            *(bf16x8*)&bs[cc * 512 + lane * 8] = h;
            *(bf16x8*)&bs[(cc + 16) * 512 + lane * 8] = l;
        }
    };

    // --- A fragments with inline hi/lo split — 16 rows per wave, once
    bf16x8 ah[8], al[8];
    {
        const int row = m0 + i16;
#pragma unroll
        for (int kc = 0; kc < 8; ++kc) {
            const size_t ab = (size_t)row * 256 + kc * 32 + quad * 8;
            const f32x4 u0 = *(const f32x4*)&A[ab];
            const f32x4 u1 = *(const f32x4*)&A[ab + 4];
#pragma unroll
            for (int e = 0; e < 4; ++e) {
                const bf16 h0 = (bf16)u0[e], h1 = (bf16)u1[e];
                ah[kc][e] = h0;
                ah[kc][e + 4] = h1;
                al[kc][e] = (bf16)(u0[e] - (float)h0);
                al[kc][e + 4] = (bf16)(u1[e] - (float)h1);
            }
        }
    }

    auto run_tile = [&](const bf16* bs, f32x4 (&acc)[2]) {
#pragma unroll
        for (int nsi = 0; nsi < 2; ++nsi) {
            acc[nsi] = f32x4{0.f, 0.f, 0.f, 0.f};
#pragma unroll
            for (int kc = 0; kc < 8; ++kc) {
                const bf16x8 bh = *(const bf16x8*)&bs[(nsi * 8 + kc) * 512 + lane * 8];
                const bf16x8 bl = *(const bf16x8*)&bs[((2 + nsi) * 8 + kc) * 512 + lane * 8];
                acc[nsi] = MFMA(ah[kc], bh, acc[nsi]);
                acc[nsi] = MFMA(ah[kc], bl, acc[nsi]);
                acc[nsi] = MFMA(al[kc], bh, acc[nsi]);
            }
        }
    };

    stage_panel(Bs[0], g);                 // Q panel
    if (t < 64) {    // pe-projection for head g / this token tile (V phase)
        const int n = mb * 64 + t;
        float acc = bpe[g];
#pragma unroll
        for (int k = 0; k < 16; ++k) acc += pe[n * 16 + k] * Wpe[k * 8 + g];
        eps[t] = __builtin_amdgcn_exp2f(-acc * LOG2E - 8.0f);
    }
    __syncthreads();                       // Bs[0] ready

    // ---- Phase Q (ct = g) ----
    stage_panel(Bs[1], 8 + g);             // prefetch K panel
    {
        f32x4 acc[2];
        run_tile(Bs[0], acc);
        const int n0 = g * 32;
#pragma unroll
        for (int nsi = 0; nsi < 2; ++nsi) {
            const int n = n0 + nsi * 16 + i16;
            const float b = bqkv[n] * SC2;
#pragma unroll
            for (int r = 0; r < 4; ++r)
                Qb[(size_t)(m0 + quad * 4 + r) * 256 + n] =
                    (bf16)(acc[nsi][r] + b);
        }
    }
    __syncthreads();                       // Bs[1] ready; Bs[0] reads done

    // ---- Phase K (ct = 8+g, head g) ----
    stage_panel(Bs[0], 16 + g);            // prefetch V panel (Bs[0] free)
    {
        f32x4 acc[2];
        run_tile(Bs[1], acc);
        const int n0 = (8 + g) * 32;
#pragma unroll
        for (int nsi = 0; nsi < 2; ++nsi) {
            const int n = n0 + nsi * 16 + i16;
            const float b = bqkv[n];
#pragma unroll
            for (int r = 0; r < 4; ++r)
                Ctl[(wave * 16 + quad * 4 + r) * 36 + nsi * 16 + i16] =
                    (bf16)(acc[nsi][r] + b);
        }
        __syncthreads();                   // Ctl ready (also: Bs[0] staged)
        // K frags: 4 chunks (4 key-subs), transpose reads; wave w takes s=w
        {
            const int s = wave;
            bf16x8 o;
#pragma unroll
            for (int j = 0; j < 8; ++j)
                o[j] = Ctl[(s * 16 + i16) * 36 + quad * 8 + j];
            *(bf16x8*)&Kf[((size_t)(g * 64 + mb) * 4 + s) * 512 + lane * 8] = o;
        }
    }
    __syncthreads();                       // K-transpose reads of Ctl done

    // ---- Phase V (ct = 16+g, head g) ----
    {
        f32x4 acc[2];
        run_tile(Bs[0], acc);
        const int n0 = (16 + g) * 32;
#pragma unroll
        for (int nsi = 0; nsi < 2; ++nsi) {
            const int n = n0 + nsi * 16 + i16;
            const float b = bqkv[n];
#pragma unroll
            for (int r = 0; r < 4; ++r)
                Ctl[(wave * 16 + quad * 4 + r) * 36 + nsi * 16 + i16] =
                    (bf16)(acc[nsi][r] + b);
        }
        __syncthreads();                   // Ctl ready; Bs[0] reads done
        // V'' frags: 6 chunks (3 d-tiles x 2 key-halves), ep-scaled,
        // ep-row at dim'=32 (softmax-l trick)
#pragma unroll
        for (int c = wave; c < 6; c += 4) {
            const int ch = c;
            const int dt = ch >> 1, kc = ch & 1;
            const int dimp = dt * 16 + i16;
            bf16x8 o;
#pragma unroll
            for (int j = 0; j < 8; ++j) {
                const int key = kc * 32 + quad * 8 + j;   // local row 0..63
                float v;
                if (dimp < 32)       v = (float)Ctl[key * 36 + dimp] * eps[key];
                else if (dimp == 32) v = eps[key];
                else                 v = 0.f;
                o[j] = (bf16)v;
            }
            *(bf16x8*)&Vf[((size_t)(g * 64 + mb) * 6 + ch) * 512 + lane * 8] = o;
        }
    }
}

// ---------------------------------------------------------------------------
// Staged 3-term split-bf16 GEMM — out proj (round-10, proven at 117.04).
// Grid (64,8), NTILE=32, 64-row m-panels, two interleaved accumulator chains.
// ---------------------------------------------------------------------------
template <int NOUT, typename OT>
__global__ __launch_bounds__(256, 2) void gemm3s_kernel(const bf16* __restrict__ Ah,
                                                        const bf16* __restrict__ Al,
                                                        const float* __restrict__ Wout,
                                                        const float* __restrict__ bias,
                                                        OT* __restrict__ C) {
    const int t = threadIdx.x, wave = t >> 6, lane = t & 63;
    const int quad = lane >> 4, i16 = lane & 15;
    const int m0 = blockIdx.x * 64 + wave * 16;
    const int n0 = blockIdx.y * 32;

    __shared__ __align__(16) bf16 Bs[32 * 512];   // 32 KB

    {   // stage B panel with inline hi/lo cast from fp32 Wout [k][n]
        const int i16l = lane & 15, ql = lane >> 4;
#pragma unroll
        for (int cc = wave; cc < 16; cc += 4) {
            const int nsi = cc >> 3, kc = cc & 7;
            const int n = n0 + nsi * 16 + i16l;
            const int kk = kc * 32 + ql * 8;
            bf16x8 h, lo;
#pragma unroll
            for (int j = 0; j < 8; ++j) {
                const float v = Wout[(size_t)(kk + j) * 256 + n];
                const bf16 hh = (bf16)v;
                h[j] = hh;
                lo[j] = (bf16)(v - (float)hh);
            }
            *(bf16x8*)&Bs[cc * 512 + lane * 8] = h;
            *(bf16x8*)&Bs[(cc + 16) * 512 + lane * 8] = lo;
        }
    }

    bf16x8 ah[8], al[8];
    {
        const size_t abase = (size_t)(m0 + i16) * 256 + quad * 8;
#pragma unroll
        for (int kc = 0; kc < 8; ++kc) {
            ah[kc] = *(const bf16x8*)&Ah[abase + kc * 32];
            al[kc] = *(const bf16x8*)&Al[abase + kc * 32];
        }
    }
    __syncthreads();

    f32x4 acc[2];
    acc[0] = f32x4{0.f, 0.f, 0.f, 0.f};
    acc[1] = f32x4{0.f, 0.f, 0.f, 0.f};
#pragma unroll
    for (int kc = 0; kc < 8; ++kc) {
#pragma unroll
        for (int nsi = 0; nsi < 2; ++nsi) {
            const bf16x8 bh = *(const bf16x8*)&Bs[(nsi * 8 + kc) * 512 + lane * 8];
            const bf16x8 bl = *(const bf16x8*)&Bs[((2 + nsi) * 8 + kc) * 512 + lane * 8];
            acc[nsi] = MFMA(ah[kc], bh, acc[nsi]);
            acc[nsi] = MFMA(ah[kc], bl, acc[nsi]);
            acc[nsi] = MFMA(al[kc], bh, acc[nsi]);
        }
    }
#pragma unroll
    for (int nsi = 0; nsi < 2; ++nsi) {
        const int n = n0 + nsi * 16 + i16;
        const float b = bias[n];
#pragma unroll
        for (int r = 0; r < 4; ++r)
            C[(size_t)(m0 + quad * 4 + r) * NOUT + n] = (OT)(acc[nsi][r] + b);
    }
}

// ---------------------------------------------------------------------------
// Fixed-m flash attention, permlane edition.  Main loop = ROUND-4 EXACT
// (frozen).  Round-11 touches ONLY the epilogue LDS layout: the merge buffer
// rows are 8 floats (32 B), so lanes l and l+4 started in the same bank —
// a structural 2x bank conflict on every b128 write/read since R0.  Fix:
// XOR-swizzle the column-half within each row (physical half = logical half
// ^ ((r>>2)&1)); lanes 0-7 then cover all 32 banks exactly once per phase.
// Same mapping on write and read; 16B alignment preserved; zero size change;
// every output gets identical summands in identical ww order -> bit-identical.
// ---------------------------------------------------------------------------
__global__ __launch_bounds__(512, 4) void attn_kernel(const bf16* __restrict__ Qb,
                                                      const bf16* __restrict__ Kf,
                                                      const bf16* __restrict__ Vf,
                                                      bf16* __restrict__ aoh,
                                                      bf16* __restrict__ aol) {
    const int t = threadIdx.x, w = t >> 6, lane = t & 63;
    const int quad = lane >> 4, i16 = lane & 15;
    const int qb = blockIdx.y, h = blockIdx.x;

    __shared__ __align__(16) float M[8][2112];   // 67.6 KB epilogue merge

    const int q0 = qb * 64;
    bf16x8 qf[4];
#pragma unroll
    for (int qs = 0; qs < 4; ++qs)
        qf[qs] = *(const bf16x8*)&Qb[(size_t)(q0 + qs * 16 + i16) * 256 + h * 32 + quad * 8];

    f32x4 o[3][4];
#pragma unroll
    for (int dt = 0; dt < 3; ++dt)
#pragma unroll
        for (int qs = 0; qs < 4; ++qs) o[dt][qs] = f32x4{0.f, 0.f, 0.f, 0.f};

    const bf16* kb = Kf + (size_t)(h * 64) * 2048 + lane * 8;
    const bf16* vb = Vf + (size_t)(h * 64) * 3072 + lane * 8;

    const int kt0 = w * 8;
    for (int it = 0; it < 8; ++it) {
        const int kt = kt0 + it;
        bf16x8 kcur[4];
#pragma unroll
        for (int s = 0; s < 4; ++s)
            kcur[s] = *(const bf16x8*)&kb[((size_t)kt * 4 + s) * 512];

        const f32x4 z = {0.f, 0.f, 0.f, 0.f};
        u32x4 P[4][2];   // [qs][32-key half] -> PV B-frag words (all static idx)
#pragma unroll
        for (int qh = 0; qh < 2; ++qh) {
            f32x4 sf[2][4];
#pragma unroll
            for (int ks = 0; ks < 4; ++ks) {
                sf[0][ks] = MFMA(kcur[ks], qf[qh * 2 + 0], z);
                sf[1][ks] = MFMA(kcur[ks], qf[qh * 2 + 1], z);
            }
#pragma unroll
            for (int qi = 0; qi < 2; ++qi) {
                const int qs = qh * 2 + qi;
#pragma unroll
                for (int h2 = 0; h2 < 2; ++h2) {
                    const f32x4 s0 = sf[qi][2 * h2 + 0];
                    const f32x4 s1 = sf[qi][2 * h2 + 1];
                    u32 a = pkbf(__builtin_amdgcn_exp2f(s0[0]),
                                 __builtin_amdgcn_exp2f(s0[1]));
                    u32 b = pkbf(__builtin_amdgcn_exp2f(s0[2]),
                                 __builtin_amdgcn_exp2f(s0[3]));
                    u32 c = pkbf(__builtin_amdgcn_exp2f(s1[0]),
                                 __builtin_amdgcn_exp2f(s1[1]));
                    u32 d = pkbf(__builtin_amdgcn_exp2f(s1[2]),
                                 __builtin_amdgcn_exp2f(s1[3]));
                    asm("v_permlane32_swap_b32 %0, %1" : "+v"(a), "+v"(c));
                    asm("v_permlane16_swap_b32 %0, %1" : "+v"(a), "+v"(c));
                    asm("v_permlane32_swap_b32 %0, %1" : "+v"(b), "+v"(d));
                    asm("v_permlane16_swap_b32 %0, %1" : "+v"(b), "+v"(d));
                    P[qs][h2] = u32x4{a, b, c, d};
                }
            }
        }

        bf16x8 vv[6];
#pragma unroll
        for (int c = 0; c < 6; ++c)
            vv[c] = *(const bf16x8*)&vb[((size_t)kt * 6 + c) * 512];

#pragma unroll
        for (int qs = 0; qs < 4; ++qs) {
            const bf16x8 pb0 = __builtin_bit_cast(bf16x8, P[qs][0]);
            const bf16x8 pb1 = __builtin_bit_cast(bf16x8, P[qs][1]);
#pragma unroll
            for (int dt = 0; dt < 3; ++dt) {
                o[dt][qs] = MFMA(vv[dt * 2 + 0], pb0, o[dt][qs]);
                o[dt][qs] = MFMA(vv[dt * 2 + 1], pb1, o[dt][qs]);
            }
        }
    }

    {
        float* myo = &M[w][0];
        const int sw = (lane >> 2) & 1;          // == ((qs*64+lane)>>2)&1
#pragma unroll
        for (int qs = 0; qs < 4; ++qs) {
            const int r = qs * 64 + lane;
            *(f32x4*)&myo[r * 8 + sw * 4]       = o[0][qs];
            *(f32x4*)&myo[r * 8 + (sw ^ 1) * 4] = o[1][qs];
        }
        if (quad == 0) {
#pragma unroll
            for (int qs = 0; qs < 4; ++qs)
                myo[2048 + qs * 16 + i16] = o[2][qs][0];
        }
    }
    __syncthreads();
    {
        const int rg = w & 3, cs = w >> 2;       // row-group, column-half
        const int sw = (lane >> 2) & 1;
        const int sel = ((cs ^ sw) << 2);        // swizzled half offset
        f32x4 a = {0.f, 0.f, 0.f, 0.f};
        float lsum = 0.f;
#pragma unroll
        for (int ww = 0; ww < 8; ++ww) {
            const float* p = &M[ww][0];
            a += *(const f32x4*)&p[(rg * 64 + lane) * 8 + sel];
            if (lane < 16) lsum += p[2048 + rg * 16 + lane];
        }
        const float linv = 1.0f / __shfl(lsum, i16, 64);
        const int row = q0 + rg * 16 + i16;
        bf16x4 hi, lo;
#pragma unroll
        for (int r = 0; r < 4; ++r) {
            const float v = a[r] * linv;
            hi[r] = (bf16)v;
            lo[r] = (bf16)(v - (float)hi[r]);
        }
        const size_t ob = (size_t)row * 256 + h * 32 + cs * 16 + quad * 4;
        *(bf16x4*)&aoh[ob] = hi;
        *(bf16x4*)&aol[ob] = lo;
    }
}

// ---------------------------------------------------------------------------
extern "C" void kernel_launch(void* const* d_in, const int* in_sizes, int n_in,
                              void* d_out, int out_size, void* d_ws, size_t ws_size,
                              hipStream_t stream) {
    const float* x    = (const float*)d_in[0];
    const float* pe   = (const float*)d_in[1];
    const float* Wqkv = (const float*)d_in[2];
    const float* bqkv = (const float*)d_in[3];
    const float* Wpe  = (const float*)d_in[4];
    const float* bpe  = (const float*)d_in[5];
    const float* Wout = (const float*)d_in[6];
    const float* bout = (const float*)d_in[7];
    float* out = (float*)d_out;

    char* ws = (char*)d_ws;
    // first 1 MB intentionally unused (was Wqkv/Wout bf16 buffers; casts inline)
    bf16*  Qb      = (bf16*)(ws + 1048576);         // 2 MB
    bf16*  Kf      = (bf16*)(ws + 3145728);         // 2 MB
    bf16*  Vf      = (bf16*)(ws + 5242880);         // 3 MB
    bf16*  aoh     = (bf16*)(ws + 8388608);         // 2 MB
    bf16*  aol     = (bf16*)(ws + 10485760);        // 2 MB -> 12.6 MB total

    gemmqkv_kernel<<<dim3(64, 8), 256, 0, stream>>>(x, Wqkv, bqkv,
                                                    pe, Wpe, bpe,
                                                    Qb, Kf, Vf);
    attn_kernel<<<dim3(HH, NN / 64), 512, 0, stream>>>(Qb, Kf, Vf, aoh, aol);
    gemm3s_kernel<256, float><<<dim3(64, 8), 256, 0, stream>>>(aoh, aol, Wout, bout, out);
}